// Round 3
// baseline (1565.962 us; speedup 1.0000x reference)
//
#include <hip/hip_runtime.h>
#include <hip/hip_bf16.h>

#define NN 20000
#define EE 320000
#define IN 128
#define HID 64
#define OUTC 128
#define NH 3
#define NEG 0.15f
#define IN2 320
#define HO1 192   // NH*HID
#define HO2 384   // NH*OUTC

typedef __hip_bfloat16 bf16;
__device__ __forceinline__ float bf2f(bf16 v) { return __bfloat162float(v); }
__device__ __forceinline__ bf16 f2bf(float v) { return __float2bfloat16(v); }

// layer-1 linear: xl = x@Wl+bl, xr = x@Wr+br (all fp32 in) ; outputs bf16.
// grid=NN, block=HO1(192)
__global__ void gemm1(const float* __restrict__ x,
                      const float* __restrict__ Wl, const float* __restrict__ bl,
                      const float* __restrict__ Wr, const float* __restrict__ br,
                      bf16* __restrict__ xl, bf16* __restrict__ xr) {
    __shared__ float xs[IN];
    const int i = blockIdx.x;
    const int o = threadIdx.x;             // 0..191
    if (o < IN) xs[o] = x[(size_t)i * IN + o];
    __syncthreads();
    float al = bl[o];
    float ar = br[o];
    for (int k = 0; k < IN; ++k) {
        const float xv = xs[k];
        al += xv * Wl[k * HO1 + o];
        ar += xv * Wr[k * HO1 + o];
    }
    xl[(size_t)i * HO1 + o] = f2bf(al);
    xr[(size_t)i * HO1 + o] = f2bf(ar);
}

// layer-1 edges: one 64-lane wave per (edge, head); C=HID=64 -> one channel/lane
__global__ void edge_agg1(const int* __restrict__ ei,
                          const bf16* __restrict__ xl, const bf16* __restrict__ xr,
                          const float* __restrict__ att,
                          float* __restrict__ acc, float* __restrict__ denom) {
    const int gw = (blockIdx.x * blockDim.x + threadIdx.x) >> 6;
    const int lane = threadIdx.x & 63;
    if (gw >= EE * NH) return;
    const int e = gw / NH;
    const int h = gw - e * NH;
    const int j = ei[e];        // src
    const int i = ei[EE + e];   // dst

    const float lv = bf2f(xl[(size_t)j * HO1 + h * HID + lane]);
    const float rv = bf2f(xr[(size_t)i * HO1 + h * HID + lane]);
    float s = lv + rv;
    s = s > 0.f ? s : NEG * s;
    float p = s * att[h * HID + lane];
#pragma unroll
    for (int off = 32; off > 0; off >>= 1) p += __shfl_xor(p, off, 64);
    const float ex = __expf(p);   // no max-subtraction: |logit| <~ 8, exp safe in fp32

    atomicAdd(&acc[(size_t)i * HO1 + h * HID + lane], ex * lv);
    if (lane == 0) atomicAdd(&denom[i * NH + h], ex);
}

// h1 = relu(acc/denom + bias) -> bf16
__global__ void finalize1(const float* __restrict__ acc, const float* __restrict__ denom,
                          const float* __restrict__ bias, bf16* __restrict__ h1) {
    const int idx = blockIdx.x * blockDim.x + threadIdx.x;
    if (idx >= NN * HO1) return;
    const int i = idx / HO1;
    const int o = idx - i * HO1;
    const int h = o >> 6;
    const float v = acc[idx] / (denom[i * NH + h] + 1e-16f) + bias[o];
    h1[idx] = f2bf(v > 0.f ? v : 0.f);
}

// layer-2 linear for ONE head: cols [h*OUTC,(h+1)*OUTC). grid=NN, block=OUTC(128)
__global__ void gemm2h(const float* __restrict__ x, const bf16* __restrict__ h1,
                       const float* __restrict__ Wl, const float* __restrict__ bl,
                       const float* __restrict__ Wr, const float* __restrict__ br,
                       bf16* __restrict__ xlh, bf16* __restrict__ xrh, int h) {
    __shared__ float hs[IN2];
    const int i = blockIdx.x;
    const int o = threadIdx.x;             // 0..127
    for (int t = o; t < IN2; t += OUTC)
        hs[t] = (t < IN) ? x[(size_t)i * IN + t] : bf2f(h1[(size_t)i * HO1 + (t - IN)]);
    __syncthreads();
    const int col = h * OUTC + o;
    float al = bl[col];
    float ar = br[col];
    for (int k = 0; k < IN2; ++k) {
        const float xv = hs[k];
        al += xv * Wl[k * HO2 + col];
        ar += xv * Wr[k * HO2 + col];
    }
    xlh[(size_t)i * OUTC + o] = f2bf(al);
    xrh[(size_t)i * OUTC + o] = f2bf(ar);
}

// layer-2 edges for ONE head: one wave per edge; C=OUTC=128 -> 2 channels/lane
__global__ void edge_agg2h(const int* __restrict__ ei,
                           const bf16* __restrict__ xlh, const bf16* __restrict__ xrh,
                           const float* __restrict__ atth,
                           float* __restrict__ acch, float* __restrict__ denh) {
    const int gw = (blockIdx.x * blockDim.x + threadIdx.x) >> 6;
    const int lane = threadIdx.x & 63;
    if (gw >= EE) return;
    const int j = ei[gw];
    const int i = ei[EE + gw];

    const float lv0 = bf2f(xlh[(size_t)j * OUTC + lane]);
    const float lv1 = bf2f(xlh[(size_t)j * OUTC + 64 + lane]);
    const float rv0 = bf2f(xrh[(size_t)i * OUTC + lane]);
    const float rv1 = bf2f(xrh[(size_t)i * OUTC + 64 + lane]);
    float s0 = lv0 + rv0; s0 = s0 > 0.f ? s0 : NEG * s0;
    float s1 = lv1 + rv1; s1 = s1 > 0.f ? s1 : NEG * s1;
    float p = s0 * atth[lane] + s1 * atth[64 + lane];
#pragma unroll
    for (int off = 32; off > 0; off >>= 1) p += __shfl_xor(p, off, 64);
    const float ex = __expf(p);

    atomicAdd(&acch[(size_t)i * OUTC + lane], ex * lv0);
    atomicAdd(&acch[(size_t)i * OUTC + 64 + lane], ex * lv1);
    if (lane == 0) atomicAdd(&denh[i], ex);
}

// outacc (fp32, = d_out region) (+)= acch/denh ; assign when first!=0
__global__ void accum2h(const float* __restrict__ acch, const float* __restrict__ denh,
                        float* __restrict__ outacc, int first) {
    const int idx = blockIdx.x * blockDim.x + threadIdx.x;
    if (idx >= NN * OUTC) return;
    const int i = idx >> 7;   // / OUTC
    const float v = acch[idx] / (denh[i] + 1e-16f);
    outacc[idx] = first ? v : (outacc[idx] + v);
}

// out = relu(out/NH + bias) in place (fp32 output)
__global__ void finalize2(float* __restrict__ out, const float* __restrict__ bias) {
    const int idx = blockIdx.x * blockDim.x + threadIdx.x;
    if (idx >= NN * OUTC) return;
    const int o = idx & (OUTC - 1);
    const float v = out[idx] * (1.f / 3.f) + bias[o];
    out[idx] = v > 0.f ? v : 0.f;
}

extern "C" void kernel_launch(void* const* d_in, const int* in_sizes, int n_in,
                              void* d_out, int out_size, void* d_ws, size_t ws_size,
                              hipStream_t stream) {
    const float* x    = (const float*)d_in[0];
    const float* Wl1  = (const float*)d_in[1];
    const float* bl1  = (const float*)d_in[2];
    const float* Wr1  = (const float*)d_in[3];
    const float* br1  = (const float*)d_in[4];
    const float* att1 = (const float*)d_in[5];
    const float* bias1= (const float*)d_in[6];
    const float* Wl2  = (const float*)d_in[7];
    const float* bl2  = (const float*)d_in[8];
    const float* Wr2  = (const float*)d_in[9];
    const float* br2  = (const float*)d_in[10];
    const float* att2 = (const float*)d_in[11];
    const float* bias2= (const float*)d_in[12];
    const int*   ei   = (const int*)d_in[13];

    char* ws = (char*)d_ws;
    // Pool layout (bytes), total ~31.0 MB:
    //   R0 [0,        7,680,000)  xl1b (bf16 [N,192]) -> h1b after finalize1
    //   R1 [7.68e6,  15,360,000)  xr1b (bf16 [N,192]) -> xl2h (bf16 [N,128], 5.12 MB)
    //   R2 [15.36e6, 30,720,000)  acc1 (f32 [N,192])  -> xr2h (bf16, 5.12 MB) + acc2h (f32, 10.24 MB)
    //   R3 [30.72e6, 30,960,000)  denom (f32; L1: NN*NH, L2: NN per head)
    bf16*  xl1b  = (bf16*)(ws);
    bf16*  xr1b  = (bf16*)(ws + 7680000);
    float* acc1  = (float*)(ws + 15360000);
    float* den   = (float*)(ws + 30720000);
    bf16*  h1b   = xl1b;                      // alias: xl1b dead after edge_agg1
    bf16*  xl2h  = xr1b;                      // alias: xr1b dead after edge_agg1
    bf16*  xr2h  = (bf16*)(ws + 15360000);    // alias: acc1 dead after finalize1
    float* acc2h = (float*)(ws + 20480000);
    float* outacc= (float*)d_out;             // cross-head fp32 accumulator = output

    // ---- layer 1 ----
    hipMemsetAsync(acc1, 0, (size_t)NN * HO1 * sizeof(float), stream);
    hipMemsetAsync(den, 0, (size_t)NN * NH * sizeof(float), stream);
    gemm1<<<NN, HO1, 0, stream>>>(x, Wl1, bl1, Wr1, br1, xl1b, xr1b);
    edge_agg1<<<(EE * NH) / 4, 256, 0, stream>>>(ei, xl1b, xr1b, att1, acc1, den);
    finalize1<<<(NN * HO1 + 255) / 256, 256, 0, stream>>>(acc1, den, bias1, h1b);

    // ---- layer 2, per head ----
    for (int h = 0; h < NH; ++h) {
        gemm2h<<<NN, OUTC, 0, stream>>>(x, h1b, Wl2, bl2, Wr2, br2, xl2h, xr2h, h);
        hipMemsetAsync(acc2h, 0, (size_t)NN * OUTC * sizeof(float), stream);
        hipMemsetAsync(den, 0, (size_t)NN * sizeof(float), stream);
        edge_agg2h<<<EE / 4, 256, 0, stream>>>(ei, xl2h, xr2h, att2 + h * OUTC, acc2h, den);
        accum2h<<<(NN * OUTC + 255) / 256, 256, 0, stream>>>(acc2h, den, outacc, h == 0 ? 1 : 0);
    }
    finalize2<<<(NN * OUTC + 255) / 256, 256, 0, stream>>>(outacc, bias2);
}

// Round 4
// 609.794 us; speedup vs baseline: 2.5680x; 2.5680x over previous
//
#include <hip/hip_runtime.h>
#include <hip/hip_bf16.h>

#define NN 20000
#define EE 320000
#define IN 128
#define HID 64
#define OUTC 128
#define NH 3
#define NEG 0.15f
#define IN2 320
#define HO1 192   // NH*HID
#define HO2 384   // NH*OUTC
#define RT 8      // rows per gemm block
#define NB_SCAN 79  // ceil(NN/256)

typedef __hip_bfloat16 bf16;
__device__ __forceinline__ float bf2f(bf16 v) { return __bfloat162float(v); }
__device__ __forceinline__ bf16 f2bf(float v) { return __float2bfloat16(v); }

// ---------------- CSR build (by dst) ----------------
__global__ void k_count(const int* __restrict__ ei, int* __restrict__ cnt) {
    const int e = blockIdx.x * 256 + threadIdx.x;
    if (e < EE) atomicAdd(&cnt[ei[EE + e]], 1);
}

__global__ void k_scanA(const int* __restrict__ cnt, int* __restrict__ loc,
                        int* __restrict__ bsum) {
    __shared__ int sh[256];
    const int t = threadIdx.x;
    const int i = blockIdx.x * 256 + t;
    const int v = (i < NN) ? cnt[i] : 0;
    sh[t] = v; __syncthreads();
    for (int off = 1; off < 256; off <<= 1) {
        const int add = (t >= off) ? sh[t - off] : 0;
        __syncthreads();
        sh[t] += add; __syncthreads();
    }
    if (i < NN) loc[i] = sh[t];            // inclusive scan within block
    if (t == 255) bsum[blockIdx.x] = sh[255];
}

__global__ void k_scanB(int* __restrict__ bsum) {   // 1 block, 128 threads; in-place -> exclusive
    __shared__ int sh[128];
    const int t = threadIdx.x;
    const int v = (t < NB_SCAN) ? bsum[t] : 0;
    sh[t] = v; __syncthreads();
    for (int off = 1; off < 128; off <<= 1) {
        const int add = (t >= off) ? sh[t - off] : 0;
        __syncthreads();
        sh[t] += add; __syncthreads();
    }
    if (t < NB_SCAN) bsum[t] = sh[t] - v;  // exclusive block offset
}

__global__ void k_scanC(const int* __restrict__ loc, const int* __restrict__ cnt,
                        const int* __restrict__ bsum, int* __restrict__ row_off,
                        int* __restrict__ fill) {
    const int i = blockIdx.x * 256 + threadIdx.x;
    if (i < NN) {
        const int ro = loc[i] - cnt[i] + bsum[blockIdx.x];
        row_off[i] = ro; fill[i] = ro;
    }
    if (i == 0) row_off[NN] = EE;
}

__global__ void k_scatter(const int* __restrict__ ei, int* __restrict__ fill,
                          int* __restrict__ csr_src) {
    const int e = blockIdx.x * 256 + threadIdx.x;
    if (e < EE) {
        const int p = atomicAdd(&fill[ei[EE + e]], 1);
        csr_src[p] = ei[e];
    }
}

// ---------------- GEMMs (8-row tiles, x staged k-major in LDS) ----------------
// block=384 threads: t<192 -> xl col t, else xr col t-192. grid=NN/RT.
__global__ void gemm1(const float* __restrict__ x,
                      const float* __restrict__ Wl, const float* __restrict__ bl,
                      const float* __restrict__ Wr, const float* __restrict__ br,
                      bf16* __restrict__ xl, bf16* __restrict__ xr) {
    __shared__ float xs[IN * RT];           // [k][r]
    const int r0 = blockIdx.x * RT;
    const int t = threadIdx.x;
    for (int u = t; u < IN * RT; u += 384) {
        const int k = u >> 3, r = u & 7;
        xs[u] = x[(size_t)(r0 + r) * IN + k];
    }
    __syncthreads();
    const bool isl = t < HO1;
    const int c = isl ? t : t - HO1;
    const float* W = (isl ? Wl : Wr) + c;
    const float b = isl ? bl[c] : br[c];
    float acc[RT];
#pragma unroll
    for (int r = 0; r < RT; ++r) acc[r] = b;
#pragma unroll 4
    for (int k = 0; k < IN; ++k) {
        const float w = W[(size_t)k * HO1];
        const float4 x0 = *(const float4*)&xs[k * RT];
        const float4 x1 = *(const float4*)&xs[k * RT + 4];
        acc[0] += x0.x * w; acc[1] += x0.y * w; acc[2] += x0.z * w; acc[3] += x0.w * w;
        acc[4] += x1.x * w; acc[5] += x1.y * w; acc[6] += x1.z * w; acc[7] += x1.w * w;
    }
    bf16* out = isl ? xl : xr;
#pragma unroll
    for (int r = 0; r < RT; ++r)
        out[(size_t)(r0 + r) * HO1 + c] = f2bf(acc[r]);
}

// block=256 threads: t<128 -> xl col (h*128+t), else xr. grid=NN/RT.
__global__ void gemm2h(const float* __restrict__ x, const bf16* __restrict__ h1,
                       const float* __restrict__ Wl, const float* __restrict__ bl,
                       const float* __restrict__ Wr, const float* __restrict__ br,
                       bf16* __restrict__ xlh, bf16* __restrict__ xrh, int h) {
    __shared__ float hs[IN2 * RT];          // [k][r]
    const int r0 = blockIdx.x * RT;
    const int t = threadIdx.x;
    for (int u = t; u < IN2 * RT; u += 256) {
        const int k = u >> 3, r = u & 7;
        hs[u] = (k < IN) ? x[(size_t)(r0 + r) * IN + k]
                         : bf2f(h1[(size_t)(r0 + r) * HO1 + (k - IN)]);
    }
    __syncthreads();
    const bool isl = t < OUTC;
    const int c = isl ? t : t - OUTC;
    const int col = h * OUTC + c;
    const float* W = (isl ? Wl : Wr) + col;
    const float b = isl ? bl[col] : br[col];
    float acc[RT];
#pragma unroll
    for (int r = 0; r < RT; ++r) acc[r] = b;
#pragma unroll 4
    for (int k = 0; k < IN2; ++k) {
        const float w = W[(size_t)k * HO2];
        const float4 x0 = *(const float4*)&hs[k * RT];
        const float4 x1 = *(const float4*)&hs[k * RT + 4];
        acc[0] += x0.x * w; acc[1] += x0.y * w; acc[2] += x0.z * w; acc[3] += x0.w * w;
        acc[4] += x1.x * w; acc[5] += x1.y * w; acc[6] += x1.z * w; acc[7] += x1.w * w;
    }
    bf16* out = isl ? xlh : xrh;
#pragma unroll
    for (int r = 0; r < RT; ++r)
        out[(size_t)(r0 + r) * OUTC + c] = f2bf(acc[r]);
}

// ---------------- gather aggregations (CSR, no atomics) ----------------
// one wave per (dst,head); lane = channel. Writes h1 = relu(out+bias) directly.
__global__ void gather1(const int* __restrict__ row_off, const int* __restrict__ csr_src,
                        const bf16* __restrict__ xl, const bf16* __restrict__ xr,
                        const float* __restrict__ att, const float* __restrict__ bias,
                        bf16* __restrict__ h1) {
    const int w = (blockIdx.x * blockDim.x + threadIdx.x) >> 6;
    const int lane = threadIdx.x & 63;
    if (w >= NN * NH) return;
    const int i = w / NH, h = w - i * NH;
    const int co = h * HID + lane;
    const float rv = bf2f(xr[(size_t)i * HO1 + co]);
    const float av = att[co];
    int k = row_off[i];
    const int e = row_off[i + 1];
    float acc = 0.f, den = 0.f;
    float lv_n = 0.f;
    if (k < e) lv_n = bf2f(xl[(size_t)csr_src[k] * HO1 + co]);
    while (k < e) {
        const float lv = lv_n;
        ++k;
        if (k < e) lv_n = bf2f(xl[(size_t)csr_src[k] * HO1 + co]);  // prefetch next row
        float s = lv + rv;
        s = s > 0.f ? s : NEG * s;
        float p = s * av;
#pragma unroll
        for (int off = 32; off > 0; off >>= 1) p += __shfl_xor(p, off, 64);
        const float ex = __expf(p);   // |logit| <~ 8: exp safe in fp32 without max-sub
        acc += ex * lv;
        den += ex;
    }
    const float v = acc / (den + 1e-16f) + bias[co];
    h1[(size_t)i * HO1 + co] = f2bf(v > 0.f ? v : 0.f);
}

// one wave per dst; lane handles channels 2l,2l+1. Accumulates head h into out.
__global__ void gather2h(const int* __restrict__ row_off, const int* __restrict__ csr_src,
                         const bf16* __restrict__ xlh, const bf16* __restrict__ xrh,
                         const float* __restrict__ atth,
                         float* __restrict__ out, int first) {
    const int i = (blockIdx.x * blockDim.x + threadIdx.x) >> 6;
    const int lane = threadIdx.x & 63;
    if (i >= NN) return;
    const int c = lane * 2;
    const __hip_bfloat162 rv2 = *(const __hip_bfloat162*)&xrh[(size_t)i * OUTC + c];
    const float rv0 = bf2f(rv2.x), rv1 = bf2f(rv2.y);
    const float2 av = *(const float2*)&atth[c];
    int k = row_off[i];
    const int e = row_off[i + 1];
    float a0 = 0.f, a1 = 0.f, den = 0.f;
    __hip_bfloat162 lv2n;
    if (k < e) lv2n = *(const __hip_bfloat162*)&xlh[(size_t)csr_src[k] * OUTC + c];
    while (k < e) {
        const float lv0 = bf2f(lv2n.x), lv1 = bf2f(lv2n.y);
        ++k;
        if (k < e) lv2n = *(const __hip_bfloat162*)&xlh[(size_t)csr_src[k] * OUTC + c];
        float s0 = lv0 + rv0; s0 = s0 > 0.f ? s0 : NEG * s0;
        float s1 = lv1 + rv1; s1 = s1 > 0.f ? s1 : NEG * s1;
        float p = s0 * av.x + s1 * av.y;
#pragma unroll
        for (int off = 32; off > 0; off >>= 1) p += __shfl_xor(p, off, 64);
        const float ex = __expf(p);
        a0 += ex * lv0; a1 += ex * lv1; den += ex;
    }
    const float inv = 1.f / (den + 1e-16f);
    float* op = out + (size_t)i * OUTC + c;
    if (first) { op[0] = a0 * inv;          op[1] = a1 * inv; }
    else       { op[0] = op[0] + a0 * inv;  op[1] = op[1] + a1 * inv; }
}

// out = relu(out/NH + bias) in place (fp32 output)
__global__ void finalize2(float* __restrict__ out, const float* __restrict__ bias) {
    const int idx = blockIdx.x * blockDim.x + threadIdx.x;
    if (idx >= NN * OUTC) return;
    const int o = idx & (OUTC - 1);
    const float v = out[idx] * (1.f / 3.f) + bias[o];
    out[idx] = v > 0.f ? v : 0.f;
}

extern "C" void kernel_launch(void* const* d_in, const int* in_sizes, int n_in,
                              void* d_out, int out_size, void* d_ws, size_t ws_size,
                              hipStream_t stream) {
    const float* x    = (const float*)d_in[0];
    const float* Wl1  = (const float*)d_in[1];
    const float* bl1  = (const float*)d_in[2];
    const float* Wr1  = (const float*)d_in[3];
    const float* br1  = (const float*)d_in[4];
    const float* att1 = (const float*)d_in[5];
    const float* bias1= (const float*)d_in[6];
    const float* Wl2  = (const float*)d_in[7];
    const float* bl2  = (const float*)d_in[8];
    const float* Wr2  = (const float*)d_in[9];
    const float* br2  = (const float*)d_in[10];
    const float* att2 = (const float*)d_in[11];
    const float* bias2= (const float*)d_in[12];
    const int*   ei   = (const int*)d_in[13];

    char* ws = (char*)d_ws;
    // Pool layout (bytes), peak ~24.7 MB (round-3's 31 MB proven OK):
    //  [0,        7,680,000)  xl1b (bf16 [N,192])  -> later xl2h (bf16 [N,128], 5.12 MB)
    //  [7.68e6,  15,360,000)  xr1b (bf16 [N,192])  -> later xr2h at 5,120,000.. (see below)
    //  [15.36e6, 23,040,000)  h1b  (bf16 [N,192])
    //  [23.04e6, ...)         CSR: cnt, fill, loc, bsum, row_off, csr_src
    bf16*  xl1b   = (bf16*)(ws);
    bf16*  xr1b   = (bf16*)(ws + 7680000);
    bf16*  h1b    = (bf16*)(ws + 15360000);
    bf16*  xl2h   = (bf16*)(ws);             // alias: xl1b/xr1b dead after gather1
    bf16*  xr2h   = (bf16*)(ws + 5120000);
    int*   cnt    = (int*)(ws + 23040000);   // 80,000 B
    int*   fill   = (int*)(ws + 23120000);   // 80,000 B
    int*   loc    = (int*)(ws + 23200000);   // 80,000 B
    int*   bsum   = (int*)(ws + 23280000);   // 4,096 B
    int*   rowoff = (int*)(ws + 23284096);   // 80,008 B
    int*   csrsrc = (int*)(ws + 23364104);   // 1,280,000 B -> end 24,644,104
    float* outacc = (float*)d_out;

    // ---- CSR build (shared by both layers) ----
    hipMemsetAsync(cnt, 0, NN * sizeof(int), stream);
    k_count<<<(EE + 255) / 256, 256, 0, stream>>>(ei, cnt);
    k_scanA<<<NB_SCAN, 256, 0, stream>>>(cnt, loc, bsum);
    k_scanB<<<1, 128, 0, stream>>>(bsum);
    k_scanC<<<NB_SCAN, 256, 0, stream>>>(loc, cnt, bsum, rowoff, fill);
    k_scatter<<<(EE + 255) / 256, 256, 0, stream>>>(ei, fill, csrsrc);

    // ---- layer 1 ----
    gemm1<<<NN / RT, 384, 0, stream>>>(x, Wl1, bl1, Wr1, br1, xl1b, xr1b);
    gather1<<<(NN * NH) / 4, 256, 0, stream>>>(rowoff, csrsrc, xl1b, xr1b, att1, bias1, h1b);

    // ---- layer 2, per head ----
    for (int h = 0; h < NH; ++h) {
        gemm2h<<<NN / RT, 256, 0, stream>>>(x, h1b, Wl2, bl2, Wr2, br2, xl2h, xr2h, h);
        gather2h<<<NN / 4, 256, 0, stream>>>(rowoff, csrsrc, xl2h, xr2h,
                                             att2 + h * OUTC, outacc, h == 0 ? 1 : 0);
    }
    finalize2<<<(NN * OUTC + 255) / 256, 256, 0, stream>>>(outacc, bias2);
}

// Round 7
// 540.298 us; speedup vs baseline: 2.8983x; 1.1286x over previous
//
#include <hip/hip_runtime.h>
#include <hip/hip_bf16.h>

#define NN 20000
#define EE 320000
#define IN 128
#define HID 64
#define OUTC 128
#define NH 3
#define NEG 0.15f
#define IN2 320
#define HO1 192   // NH*HID
#define HO2 384   // NH*OUTC
#define RT 8      // rows per gemm block
#define NB_SCAN 79  // ceil(NN/256)

typedef __hip_bfloat16 bf16;
__device__ __forceinline__ float bf2f(bf16 v) { return __bfloat162float(v); }
__device__ __forceinline__ bf16 f2bf(float v) { return __float2bfloat16(v); }

// ---------------- CSR build (by dst) — byte-identical to round 4 ----------------
__global__ void k_count(const int* __restrict__ ei, int* __restrict__ cnt) {
    const int e = blockIdx.x * 256 + threadIdx.x;
    if (e < EE) atomicAdd(&cnt[ei[EE + e]], 1);
}

__global__ void k_scanA(const int* __restrict__ cnt, int* __restrict__ loc,
                        int* __restrict__ bsum) {
    __shared__ int sh[256];
    const int t = threadIdx.x;
    const int i = blockIdx.x * 256 + t;
    const int v = (i < NN) ? cnt[i] : 0;
    sh[t] = v; __syncthreads();
    for (int off = 1; off < 256; off <<= 1) {
        const int add = (t >= off) ? sh[t - off] : 0;
        __syncthreads();
        sh[t] += add; __syncthreads();
    }
    if (i < NN) loc[i] = sh[t];            // inclusive scan within block
    if (t == 255) bsum[blockIdx.x] = sh[255];
}

__global__ void k_scanB(int* __restrict__ bsum) {   // 1 block; in-place -> exclusive
    __shared__ int sh[128];
    const int t = threadIdx.x;
    const int v = (t < NB_SCAN) ? bsum[t] : 0;
    sh[t] = v; __syncthreads();
    for (int off = 1; off < 128; off <<= 1) {
        const int add = (t >= off) ? sh[t - off] : 0;
        __syncthreads();
        sh[t] += add; __syncthreads();
    }
    if (t < NB_SCAN) bsum[t] = sh[t] - v;  // exclusive block offset
}

__global__ void k_scanC(const int* __restrict__ loc, const int* __restrict__ cnt,
                        const int* __restrict__ bsum, int* __restrict__ row_off,
                        int* __restrict__ fill) {
    const int i = blockIdx.x * 256 + threadIdx.x;
    if (i < NN) {
        const int ro = loc[i] - cnt[i] + bsum[blockIdx.x];
        row_off[i] = ro; fill[i] = ro;
    }
    if (i == 0) row_off[NN] = EE;
}

__global__ void k_scatter(const int* __restrict__ ei, int* __restrict__ fill,
                          int* __restrict__ csr_src) {
    const int e = blockIdx.x * 256 + threadIdx.x;
    if (e < EE) {
        const int p = atomicAdd(&fill[ei[EE + e]], 1);
        csr_src[p] = ei[e];
    }
}

// ---------------- GEMMs (8-row tiles) — byte-identical to round 4 ----------------
__global__ void gemm1(const float* __restrict__ x,
                      const float* __restrict__ Wl, const float* __restrict__ bl,
                      const float* __restrict__ Wr, const float* __restrict__ br,
                      bf16* __restrict__ xl, bf16* __restrict__ xr) {
    __shared__ float xs[IN * RT];           // [k][r]
    const int r0 = blockIdx.x * RT;
    const int t = threadIdx.x;
    for (int u = t; u < IN * RT; u += 384) {
        const int k = u >> 3, r = u & 7;
        xs[u] = x[(size_t)(r0 + r) * IN + k];
    }
    __syncthreads();
    const bool isl = t < HO1;
    const int c = isl ? t : t - HO1;
    const float* W = (isl ? Wl : Wr) + c;
    const float b = isl ? bl[c] : br[c];
    float acc[RT];
#pragma unroll
    for (int r = 0; r < RT; ++r) acc[r] = b;
#pragma unroll 4
    for (int k = 0; k < IN; ++k) {
        const float w = W[(size_t)k * HO1];
        const float4 x0 = *(const float4*)&xs[k * RT];
        const float4 x1 = *(const float4*)&xs[k * RT + 4];
        acc[0] += x0.x * w; acc[1] += x0.y * w; acc[2] += x0.z * w; acc[3] += x0.w * w;
        acc[4] += x1.x * w; acc[5] += x1.y * w; acc[6] += x1.z * w; acc[7] += x1.w * w;
    }
    bf16* out = isl ? xl : xr;
#pragma unroll
    for (int r = 0; r < RT; ++r)
        out[(size_t)(r0 + r) * HO1 + c] = f2bf(acc[r]);
}

__global__ void gemm2h(const float* __restrict__ x, const bf16* __restrict__ h1,
                       const float* __restrict__ Wl, const float* __restrict__ bl,
                       const float* __restrict__ Wr, const float* __restrict__ br,
                       bf16* __restrict__ xlh, bf16* __restrict__ xrh, int h) {
    __shared__ float hs[IN2 * RT];          // [k][r]
    const int r0 = blockIdx.x * RT;
    const int t = threadIdx.x;
    for (int u = t; u < IN2 * RT; u += 256) {
        const int k = u >> 3, r = u & 7;
        hs[u] = (k < IN) ? x[(size_t)(r0 + r) * IN + k]
                         : bf2f(h1[(size_t)(r0 + r) * HO1 + (k - IN)]);
    }
    __syncthreads();
    const bool isl = t < OUTC;
    const int c = isl ? t : t - OUTC;
    const int col = h * OUTC + c;
    const float* W = (isl ? Wl : Wr) + col;
    const float b = isl ? bl[col] : br[col];
    float acc[RT];
#pragma unroll
    for (int r = 0; r < RT; ++r) acc[r] = b;
#pragma unroll 4
    for (int k = 0; k < IN2; ++k) {
        const float w = W[(size_t)k * HO2];
        const float4 x0 = *(const float4*)&hs[k * RT];
        const float4 x1 = *(const float4*)&hs[k * RT + 4];
        acc[0] += x0.x * w; acc[1] += x0.y * w; acc[2] += x0.z * w; acc[3] += x0.w * w;
        acc[4] += x1.x * w; acc[5] += x1.y * w; acc[6] += x1.z * w; acc[7] += x1.w * w;
    }
    bf16* out = isl ? xlh : xrh;
#pragma unroll
    for (int r = 0; r < RT; ++r)
        out[(size_t)(r0 + r) * OUTC + c] = f2bf(acc[r]);
}

// ---------------- fused gathers (round-4 dataflow, more ILP) ----------------
// layer 1: one wave per dst covering ALL 3 heads; lane = channel within head.
// Per edge: 3 interleaved butterfly chains; xl row fetched once for all heads.
__global__ void gather1(const int* __restrict__ row_off, const int* __restrict__ csr_src,
                        const bf16* __restrict__ xl, const bf16* __restrict__ xr,
                        const float* __restrict__ att, const float* __restrict__ bias,
                        bf16* __restrict__ h1) {
    const int i = (blockIdx.x * blockDim.x + threadIdx.x) >> 6;
    const int lane = threadIdx.x & 63;
    if (i >= NN) return;
    const float rv0 = bf2f(xr[(size_t)i * HO1 + lane]);
    const float rv1 = bf2f(xr[(size_t)i * HO1 + 64 + lane]);
    const float rv2 = bf2f(xr[(size_t)i * HO1 + 128 + lane]);
    const float av0 = att[lane], av1 = att[64 + lane], av2 = att[128 + lane];
    int k = row_off[i];
    const int e = row_off[i + 1];
    float a0 = 0.f, a1 = 0.f, a2 = 0.f, d0 = 0.f, d1 = 0.f, d2 = 0.f;
    while (k < e) {
        const int j = csr_src[k]; ++k;
        const float l0 = bf2f(xl[(size_t)j * HO1 + lane]);
        const float l1 = bf2f(xl[(size_t)j * HO1 + 64 + lane]);
        const float l2 = bf2f(xl[(size_t)j * HO1 + 128 + lane]);
        float s0 = l0 + rv0; s0 = s0 > 0.f ? s0 : NEG * s0;
        float s1 = l1 + rv1; s1 = s1 > 0.f ? s1 : NEG * s1;
        float s2 = l2 + rv2; s2 = s2 > 0.f ? s2 : NEG * s2;
        float p0 = s0 * av0, p1 = s1 * av1, p2 = s2 * av2;
#pragma unroll
        for (int off = 32; off > 0; off >>= 1) {
            p0 += __shfl_xor(p0, off, 64);
            p1 += __shfl_xor(p1, off, 64);
            p2 += __shfl_xor(p2, off, 64);
        }
        const float e0 = __expf(p0), e1 = __expf(p1), e2 = __expf(p2);  // |logit|<~8: fp32-safe
        a0 += e0 * l0; a1 += e1 * l1; a2 += e2 * l2;
        d0 += e0;      d1 += e1;      d2 += e2;
    }
    const float o0 = a0 / (d0 + 1e-16f) + bias[lane];
    const float o1 = a1 / (d1 + 1e-16f) + bias[64 + lane];
    const float o2 = a2 / (d2 + 1e-16f) + bias[128 + lane];
    h1[(size_t)i * HO1 + lane]       = f2bf(o0 > 0.f ? o0 : 0.f);
    h1[(size_t)i * HO1 + 64 + lane]  = f2bf(o1 > 0.f ? o1 : 0.f);
    h1[(size_t)i * HO1 + 128 + lane] = f2bf(o2 > 0.f ? o2 : 0.f);
}

// layer 2 (one head): one wave per dst; lane = channels 2l,2l+1; 2-edge unroll.
__global__ void gather2h(const int* __restrict__ row_off, const int* __restrict__ csr_src,
                         const bf16* __restrict__ xlh, const bf16* __restrict__ xrh,
                         const float* __restrict__ atth,
                         float* __restrict__ out, int first) {
    const int i = (blockIdx.x * blockDim.x + threadIdx.x) >> 6;
    const int lane = threadIdx.x & 63;
    if (i >= NN) return;
    const int c = lane * 2;
    const __hip_bfloat162 rvv = *(const __hip_bfloat162*)&xrh[(size_t)i * OUTC + c];
    const float rv0 = bf2f(rvv.x), rv1 = bf2f(rvv.y);
    const float2 av = *(const float2*)&atth[c];
    int k = row_off[i];
    const int e = row_off[i + 1];
    float a0 = 0.f, a1 = 0.f, den = 0.f;
    for (; k + 1 < e; k += 2) {        // pairs: two interleaved chains
        const int ja = csr_src[k], jb = csr_src[k + 1];
        const __hip_bfloat162 lA = *(const __hip_bfloat162*)&xlh[(size_t)ja * OUTC + c];
        const __hip_bfloat162 lB = *(const __hip_bfloat162*)&xlh[(size_t)jb * OUTC + c];
        const float lA0 = bf2f(lA.x), lA1 = bf2f(lA.y);
        const float lB0 = bf2f(lB.x), lB1 = bf2f(lB.y);
        float sA0 = lA0 + rv0; sA0 = sA0 > 0.f ? sA0 : NEG * sA0;
        float sA1 = lA1 + rv1; sA1 = sA1 > 0.f ? sA1 : NEG * sA1;
        float sB0 = lB0 + rv0; sB0 = sB0 > 0.f ? sB0 : NEG * sB0;
        float sB1 = lB1 + rv1; sB1 = sB1 > 0.f ? sB1 : NEG * sB1;
        float pA = sA0 * av.x + sA1 * av.y;
        float pB = sB0 * av.x + sB1 * av.y;
#pragma unroll
        for (int off = 32; off > 0; off >>= 1) {
            pA += __shfl_xor(pA, off, 64);
            pB += __shfl_xor(pB, off, 64);
        }
        const float eA = __expf(pA), eB = __expf(pB);
        a0 += eA * lA0 + eB * lB0;
        a1 += eA * lA1 + eB * lB1;
        den += eA + eB;
    }
    if (k < e) {                        // tail
        const int j = csr_src[k];
        const __hip_bfloat162 lv = *(const __hip_bfloat162*)&xlh[(size_t)j * OUTC + c];
        const float l0 = bf2f(lv.x), l1 = bf2f(lv.y);
        float s0 = l0 + rv0; s0 = s0 > 0.f ? s0 : NEG * s0;
        float s1 = l1 + rv1; s1 = s1 > 0.f ? s1 : NEG * s1;
        float p = s0 * av.x + s1 * av.y;
#pragma unroll
        for (int off = 32; off > 0; off >>= 1) p += __shfl_xor(p, off, 64);
        const float ex = __expf(p);
        a0 += ex * l0; a1 += ex * l1; den += ex;
    }
    const float inv = 1.f / (den + 1e-16f);
    float* op = out + (size_t)i * OUTC + c;
    if (first) { op[0] = a0 * inv;         op[1] = a1 * inv; }
    else       { op[0] = op[0] + a0 * inv; op[1] = op[1] + a1 * inv; }
}

// out = relu(out/NH + bias) in place (fp32 output)
__global__ void finalize2(float* __restrict__ out, const float* __restrict__ bias) {
    const int idx = blockIdx.x * blockDim.x + threadIdx.x;
    if (idx >= NN * OUTC) return;
    const int o = idx & (OUTC - 1);
    const float v = out[idx] * (1.f / 3.f) + bias[o];
    out[idx] = v > 0.f ? v : 0.f;
}

extern "C" void kernel_launch(void* const* d_in, const int* in_sizes, int n_in,
                              void* d_out, int out_size, void* d_ws, size_t ws_size,
                              hipStream_t stream) {
    const float* x    = (const float*)d_in[0];
    const float* Wl1  = (const float*)d_in[1];
    const float* bl1  = (const float*)d_in[2];
    const float* Wr1  = (const float*)d_in[3];
    const float* br1  = (const float*)d_in[4];
    const float* att1 = (const float*)d_in[5];
    const float* bias1= (const float*)d_in[6];
    const float* Wl2  = (const float*)d_in[7];
    const float* bl2  = (const float*)d_in[8];
    const float* Wr2  = (const float*)d_in[9];
    const float* br2  = (const float*)d_in[10];
    const float* att2 = (const float*)d_in[11];
    const float* bias2= (const float*)d_in[12];
    const int*   ei   = (const int*)d_in[13];

    char* ws = (char*)d_ws;
    // Pool layout: EXACTLY round 4's proven layout (peak 24,644,104 B):
    //  [0,        7,680,000)  xl1b bf16 [N,192]   -> later xl2h bf16 [N,128]
    //  [7.68e6,  15,360,000)  xr1b bf16 [N,192]   -> later xr2h (at +5.12 MB)
    //  [15.36e6, 23,040,000)  h1b  bf16 [N,192]
    //  [23.04e6, 24,644,104)  CSR: cnt/fill/loc/bsum/rowoff/csrsrc
    bf16*  xl1b   = (bf16*)(ws);
    bf16*  xr1b   = (bf16*)(ws + 7680000);
    bf16*  h1b    = (bf16*)(ws + 15360000);
    bf16*  xl2h   = (bf16*)(ws);             // alias: xl1b/xr1b dead after gather1
    bf16*  xr2h   = (bf16*)(ws + 5120000);
    int*   cnt    = (int*)(ws + 23040000);
    int*   fill   = (int*)(ws + 23120000);
    int*   loc    = (int*)(ws + 23200000);
    int*   bsum   = (int*)(ws + 23280000);
    int*   rowoff = (int*)(ws + 23284096);
    int*   csrsrc = (int*)(ws + 23364104);   // end 24,644,104
    float* outacc = (float*)d_out;

    // ---- CSR build (shared by both layers) ----
    hipMemsetAsync(cnt, 0, NN * sizeof(int), stream);
    k_count<<<(EE + 255) / 256, 256, 0, stream>>>(ei, cnt);
    k_scanA<<<NB_SCAN, 256, 0, stream>>>(cnt, loc, bsum);
    k_scanB<<<1, 128, 0, stream>>>(bsum);
    k_scanC<<<NB_SCAN, 256, 0, stream>>>(loc, cnt, bsum, rowoff, fill);
    k_scatter<<<(EE + 255) / 256, 256, 0, stream>>>(ei, fill, csrsrc);

    // ---- layer 1 ----
    gemm1<<<NN / RT, 384, 0, stream>>>(x, Wl1, bl1, Wr1, br1, xl1b, xr1b);
    gather1<<<NN / 4, 256, 0, stream>>>(rowoff, csrsrc, xl1b, xr1b, att1, bias1, h1b);

    // ---- layer 2, per head ----
    for (int h = 0; h < NH; ++h) {
        gemm2h<<<NN / RT, 256, 0, stream>>>(x, h1b, Wl2, bl2, Wr2, br2, xl2h, xr2h, h);
        gather2h<<<NN / 4, 256, 0, stream>>>(rowoff, csrsrc, xl2h, xr2h,
                                             att2 + h * OUTC, outacc, h == 0 ? 1 : 0);
    }
    finalize2<<<(NN * OUTC + 255) / 256, 256, 0, stream>>>(outacc, bias2);
}

// Round 8
// 450.858 us; speedup vs baseline: 3.4733x; 1.1984x over previous
//
#include <hip/hip_runtime.h>
#include <hip/hip_bf16.h>

#define NN 20000
#define EE 320000
#define IN 128
#define HID 64
#define OUTC 128
#define NH 3
#define NEG 0.15f
#define IN2 320
#define HO1 192   // NH*HID
#define HO2 384   // NH*OUTC
#define RT 8      // rows per gemm1 block
#define RT2 16    // rows per gemm2 block
#define NB_SCAN 79  // ceil(NN/256)

typedef __hip_bfloat16 bf16;
__device__ __forceinline__ float bf2f(bf16 v) { return __bfloat162float(v); }
__device__ __forceinline__ bf16 f2bf(float v) { return __float2bfloat16(v); }
__device__ __forceinline__ float lrelu(float s) { return s > 0.f ? s : NEG * s; }

// ---------------- CSR build (by dst) — proven in rounds 4/7 ----------------
__global__ void k_count(const int* __restrict__ ei, int* __restrict__ cnt) {
    const int e = blockIdx.x * 256 + threadIdx.x;
    if (e < EE) atomicAdd(&cnt[ei[EE + e]], 1);
}

__global__ void k_scanA(const int* __restrict__ cnt, int* __restrict__ loc,
                        int* __restrict__ bsum) {
    __shared__ int sh[256];
    const int t = threadIdx.x;
    const int i = blockIdx.x * 256 + t;
    const int v = (i < NN) ? cnt[i] : 0;
    sh[t] = v; __syncthreads();
    for (int off = 1; off < 256; off <<= 1) {
        const int add = (t >= off) ? sh[t - off] : 0;
        __syncthreads();
        sh[t] += add; __syncthreads();
    }
    if (i < NN) loc[i] = sh[t];
    if (t == 255) bsum[blockIdx.x] = sh[255];
}

__global__ void k_scanB(int* __restrict__ bsum) {
    __shared__ int sh[128];
    const int t = threadIdx.x;
    const int v = (t < NB_SCAN) ? bsum[t] : 0;
    sh[t] = v; __syncthreads();
    for (int off = 1; off < 128; off <<= 1) {
        const int add = (t >= off) ? sh[t - off] : 0;
        __syncthreads();
        sh[t] += add; __syncthreads();
    }
    if (t < NB_SCAN) bsum[t] = sh[t] - v;
}

__global__ void k_scanC(const int* __restrict__ loc, const int* __restrict__ cnt,
                        const int* __restrict__ bsum, int* __restrict__ row_off,
                        int* __restrict__ fill) {
    const int i = blockIdx.x * 256 + threadIdx.x;
    if (i < NN) {
        const int ro = loc[i] - cnt[i] + bsum[blockIdx.x];
        row_off[i] = ro; fill[i] = ro;
    }
    if (i == 0) row_off[NN] = EE;
}

__global__ void k_scatter(const int* __restrict__ ei, int* __restrict__ fill,
                          int* __restrict__ csr_src) {
    const int e = blockIdx.x * 256 + threadIdx.x;
    if (e < EE) {
        const int p = atomicAdd(&fill[ei[EE + e]], 1);
        csr_src[p] = ei[e];
    }
}

// ---------------- gemm1 (unchanged from round 7) ----------------
__global__ void gemm1(const float* __restrict__ x,
                      const float* __restrict__ Wl, const float* __restrict__ bl,
                      const float* __restrict__ Wr, const float* __restrict__ br,
                      bf16* __restrict__ xl, bf16* __restrict__ xr) {
    __shared__ float xs[IN * RT];           // [k][r]
    const int r0 = blockIdx.x * RT;
    const int t = threadIdx.x;
    for (int u = t; u < IN * RT; u += 384) {
        const int k = u >> 3, r = u & 7;
        xs[u] = x[(size_t)(r0 + r) * IN + k];
    }
    __syncthreads();
    const bool isl = t < HO1;
    const int c = isl ? t : t - HO1;
    const float* W = (isl ? Wl : Wr) + c;
    const float b = isl ? bl[c] : br[c];
    float acc[RT];
#pragma unroll
    for (int r = 0; r < RT; ++r) acc[r] = b;
#pragma unroll 4
    for (int k = 0; k < IN; ++k) {
        const float w = W[(size_t)k * HO1];
        const float4 x0 = *(const float4*)&xs[k * RT];
        const float4 x1 = *(const float4*)&xs[k * RT + 4];
        acc[0] += x0.x * w; acc[1] += x0.y * w; acc[2] += x0.z * w; acc[3] += x0.w * w;
        acc[4] += x1.x * w; acc[5] += x1.y * w; acc[6] += x1.z * w; acc[7] += x1.w * w;
    }
    bf16* out = isl ? xl : xr;
#pragma unroll
    for (int r = 0; r < RT; ++r)
        out[(size_t)(r0 + r) * HO1 + c] = f2bf(acc[r]);
}

// ---------------- gemm2: ALL heads, l+r per thread, 16-row tiles ----------------
// block=384 (col t), grid=NN/RT2. LDS 20.5 KB.
__global__ void gemm2(const float* __restrict__ x, const bf16* __restrict__ h1,
                      const float* __restrict__ Wl, const float* __restrict__ bl,
                      const float* __restrict__ Wr, const float* __restrict__ br,
                      bf16* __restrict__ xl2, bf16* __restrict__ xr2) {
    __shared__ float hs[IN2 * RT2];         // [k][r]
    const int r0 = blockIdx.x * RT2;
    const int t = threadIdx.x;              // 0..383 = output col
    for (int u = t; u < IN2 * RT2; u += 384) {
        const int k = u >> 4, r = u & 15;
        hs[u] = (k < IN) ? x[(size_t)(r0 + r) * IN + k]
                         : bf2f(h1[(size_t)(r0 + r) * HO1 + (k - IN)]);
    }
    __syncthreads();
    const float bL = bl[t], bR = br[t];
    float accl[RT2], accr[RT2];
#pragma unroll
    for (int r = 0; r < RT2; ++r) { accl[r] = bL; accr[r] = bR; }
#pragma unroll 2
    for (int k = 0; k < IN2; ++k) {
        const float wl = Wl[(size_t)k * HO2 + t];
        const float wr = Wr[(size_t)k * HO2 + t];
        const float* xk = &hs[k * RT2];
#pragma unroll
        for (int r = 0; r < RT2; ++r) {
            const float xv = xk[r];
            accl[r] += xv * wl;
            accr[r] += xv * wr;
        }
    }
#pragma unroll
    for (int r = 0; r < RT2; ++r) {
        xl2[(size_t)(r0 + r) * HO2 + t] = f2bf(accl[r]);
        xr2[(size_t)(r0 + r) * HO2 + t] = f2bf(accr[r]);
    }
}

// ---------------- gather1: wave/dst, 3 heads, 2-edge unroll, shfl-broadcast ----
__global__ void gather1(const int* __restrict__ row_off, const int* __restrict__ csr_src,
                        const bf16* __restrict__ xl, const bf16* __restrict__ xr,
                        const float* __restrict__ att, const float* __restrict__ bias,
                        bf16* __restrict__ h1) {
    const int i = (blockIdx.x * blockDim.x + threadIdx.x) >> 6;
    const int lane = threadIdx.x & 63;
    if (i >= NN) return;
    const float rv0 = bf2f(xr[(size_t)i * HO1 + lane]);
    const float rv1 = bf2f(xr[(size_t)i * HO1 + 64 + lane]);
    const float rv2 = bf2f(xr[(size_t)i * HO1 + 128 + lane]);
    const float av0 = att[lane], av1 = att[64 + lane], av2 = att[128 + lane];
    int k = row_off[i];
    const int e = row_off[i + 1];
    float a0 = 0.f, a1 = 0.f, a2 = 0.f, d0 = 0.f, d1 = 0.f, d2 = 0.f;
    while (k < e) {
        const int batch = min(64, e - k);
        const int jv = (lane < batch) ? csr_src[k + lane] : 0;  // one coalesced load
        int m = 0;
        for (; m + 1 < batch; m += 2) {      // 2 edges -> 6 interleaved chains
            const int ja = __shfl(jv, m, 64);
            const int jb = __shfl(jv, m + 1, 64);
            const float lA0 = bf2f(xl[(size_t)ja * HO1 + lane]);
            const float lA1 = bf2f(xl[(size_t)ja * HO1 + 64 + lane]);
            const float lA2 = bf2f(xl[(size_t)ja * HO1 + 128 + lane]);
            const float lB0 = bf2f(xl[(size_t)jb * HO1 + lane]);
            const float lB1 = bf2f(xl[(size_t)jb * HO1 + 64 + lane]);
            const float lB2 = bf2f(xl[(size_t)jb * HO1 + 128 + lane]);
            float pA0 = lrelu(lA0 + rv0) * av0;
            float pA1 = lrelu(lA1 + rv1) * av1;
            float pA2 = lrelu(lA2 + rv2) * av2;
            float pB0 = lrelu(lB0 + rv0) * av0;
            float pB1 = lrelu(lB1 + rv1) * av1;
            float pB2 = lrelu(lB2 + rv2) * av2;
#pragma unroll
            for (int off = 32; off > 0; off >>= 1) {
                pA0 += __shfl_xor(pA0, off, 64);
                pA1 += __shfl_xor(pA1, off, 64);
                pA2 += __shfl_xor(pA2, off, 64);
                pB0 += __shfl_xor(pB0, off, 64);
                pB1 += __shfl_xor(pB1, off, 64);
                pB2 += __shfl_xor(pB2, off, 64);
            }
            const float eA0 = __expf(pA0), eA1 = __expf(pA1), eA2 = __expf(pA2);
            const float eB0 = __expf(pB0), eB1 = __expf(pB1), eB2 = __expf(pB2);
            a0 += eA0 * lA0 + eB0 * lB0; d0 += eA0 + eB0;
            a1 += eA1 * lA1 + eB1 * lB1; d1 += eA1 + eB1;
            a2 += eA2 * lA2 + eB2 * lB2; d2 += eA2 + eB2;
        }
        if (m < batch) {                     // odd tail of this batch
            const int j = __shfl(jv, m, 64);
            const float l0 = bf2f(xl[(size_t)j * HO1 + lane]);
            const float l1 = bf2f(xl[(size_t)j * HO1 + 64 + lane]);
            const float l2 = bf2f(xl[(size_t)j * HO1 + 128 + lane]);
            float p0 = lrelu(l0 + rv0) * av0;
            float p1 = lrelu(l1 + rv1) * av1;
            float p2 = lrelu(l2 + rv2) * av2;
#pragma unroll
            for (int off = 32; off > 0; off >>= 1) {
                p0 += __shfl_xor(p0, off, 64);
                p1 += __shfl_xor(p1, off, 64);
                p2 += __shfl_xor(p2, off, 64);
            }
            const float e0 = __expf(p0), e1 = __expf(p1), e2 = __expf(p2);
            a0 += e0 * l0; d0 += e0;
            a1 += e1 * l1; d1 += e1;
            a2 += e2 * l2; d2 += e2;
        }
        k += batch;
    }
    const float o0 = a0 / (d0 + 1e-16f) + bias[lane];
    const float o1 = a1 / (d1 + 1e-16f) + bias[64 + lane];
    const float o2 = a2 / (d2 + 1e-16f) + bias[128 + lane];
    h1[(size_t)i * HO1 + lane]       = f2bf(o0 > 0.f ? o0 : 0.f);
    h1[(size_t)i * HO1 + 64 + lane]  = f2bf(o1 > 0.f ? o1 : 0.f);
    h1[(size_t)i * HO1 + 128 + lane] = f2bf(o2 > 0.f ? o2 : 0.f);
}

// ---------------- gather2: wave/dst, ALL 3 heads, 2-edge unroll, fused epilogue -
// lane covers output channels 2l,2l+1 (shared across heads). Writes d_out once.
__global__ void gather2(const int* __restrict__ row_off, const int* __restrict__ csr_src,
                        const bf16* __restrict__ xl2, const bf16* __restrict__ xr2,
                        const float* __restrict__ att2, const float* __restrict__ bias2,
                        float* __restrict__ out) {
    const int i = (blockIdx.x * blockDim.x + threadIdx.x) >> 6;
    const int lane = threadIdx.x & 63;
    if (i >= NN) return;
    const int c = lane * 2;
    float rv[6], av[6];
#pragma unroll
    for (int h = 0; h < NH; ++h) {
        const __hip_bfloat162 r2 = *(const __hip_bfloat162*)&xr2[(size_t)i * HO2 + h * OUTC + c];
        rv[2 * h] = bf2f(r2.x); rv[2 * h + 1] = bf2f(r2.y);
        const float2 a2 = *(const float2*)&att2[h * OUTC + c];
        av[2 * h] = a2.x; av[2 * h + 1] = a2.y;
    }
    float acc[6] = {0.f, 0.f, 0.f, 0.f, 0.f, 0.f};
    float den[3] = {0.f, 0.f, 0.f};
    int k = row_off[i];
    const int e = row_off[i + 1];
    while (k < e) {
        const int batch = min(64, e - k);
        const int jv = (lane < batch) ? csr_src[k + lane] : 0;
        int m = 0;
        for (; m + 1 < batch; m += 2) {      // 2 edges x 3 heads -> 6 chains
            const int ja = __shfl(jv, m, 64);
            const int jb = __shfl(jv, m + 1, 64);
            float lA[6], lB[6];
#pragma unroll
            for (int h = 0; h < NH; ++h) {
                const __hip_bfloat162 A = *(const __hip_bfloat162*)&xl2[(size_t)ja * HO2 + h * OUTC + c];
                const __hip_bfloat162 B = *(const __hip_bfloat162*)&xl2[(size_t)jb * HO2 + h * OUTC + c];
                lA[2 * h] = bf2f(A.x); lA[2 * h + 1] = bf2f(A.y);
                lB[2 * h] = bf2f(B.x); lB[2 * h + 1] = bf2f(B.y);
            }
            float pA0 = lrelu(lA[0] + rv[0]) * av[0] + lrelu(lA[1] + rv[1]) * av[1];
            float pA1 = lrelu(lA[2] + rv[2]) * av[2] + lrelu(lA[3] + rv[3]) * av[3];
            float pA2 = lrelu(lA[4] + rv[4]) * av[4] + lrelu(lA[5] + rv[5]) * av[5];
            float pB0 = lrelu(lB[0] + rv[0]) * av[0] + lrelu(lB[1] + rv[1]) * av[1];
            float pB1 = lrelu(lB[2] + rv[2]) * av[2] + lrelu(lB[3] + rv[3]) * av[3];
            float pB2 = lrelu(lB[4] + rv[4]) * av[4] + lrelu(lB[5] + rv[5]) * av[5];
#pragma unroll
            for (int off = 32; off > 0; off >>= 1) {
                pA0 += __shfl_xor(pA0, off, 64);
                pA1 += __shfl_xor(pA1, off, 64);
                pA2 += __shfl_xor(pA2, off, 64);
                pB0 += __shfl_xor(pB0, off, 64);
                pB1 += __shfl_xor(pB1, off, 64);
                pB2 += __shfl_xor(pB2, off, 64);
            }
            const float eA0 = __expf(pA0), eA1 = __expf(pA1), eA2 = __expf(pA2);
            const float eB0 = __expf(pB0), eB1 = __expf(pB1), eB2 = __expf(pB2);
            acc[0] += eA0 * lA[0] + eB0 * lB[0];
            acc[1] += eA0 * lA[1] + eB0 * lB[1];
            acc[2] += eA1 * lA[2] + eB1 * lB[2];
            acc[3] += eA1 * lA[3] + eB1 * lB[3];
            acc[4] += eA2 * lA[4] + eB2 * lB[4];
            acc[5] += eA2 * lA[5] + eB2 * lB[5];
            den[0] += eA0 + eB0; den[1] += eA1 + eB1; den[2] += eA2 + eB2;
        }
        if (m < batch) {
            const int j = __shfl(jv, m, 64);
            float lv[6];
#pragma unroll
            for (int h = 0; h < NH; ++h) {
                const __hip_bfloat162 A = *(const __hip_bfloat162*)&xl2[(size_t)j * HO2 + h * OUTC + c];
                lv[2 * h] = bf2f(A.x); lv[2 * h + 1] = bf2f(A.y);
            }
            float p0 = lrelu(lv[0] + rv[0]) * av[0] + lrelu(lv[1] + rv[1]) * av[1];
            float p1 = lrelu(lv[2] + rv[2]) * av[2] + lrelu(lv[3] + rv[3]) * av[3];
            float p2 = lrelu(lv[4] + rv[4]) * av[4] + lrelu(lv[5] + rv[5]) * av[5];
#pragma unroll
            for (int off = 32; off > 0; off >>= 1) {
                p0 += __shfl_xor(p0, off, 64);
                p1 += __shfl_xor(p1, off, 64);
                p2 += __shfl_xor(p2, off, 64);
            }
            const float e0 = __expf(p0), e1 = __expf(p1), e2 = __expf(p2);
            acc[0] += e0 * lv[0]; acc[1] += e0 * lv[1];
            acc[2] += e1 * lv[2]; acc[3] += e1 * lv[3];
            acc[4] += e2 * lv[4]; acc[5] += e2 * lv[5];
            den[0] += e0; den[1] += e1; den[2] += e2;
        }
        k += batch;
    }
    const float i0 = 1.f / (den[0] + 1e-16f);
    const float i1 = 1.f / (den[1] + 1e-16f);
    const float i2 = 1.f / (den[2] + 1e-16f);
    const float2 b2 = *(const float2*)&bias2[c];
    float v0 = (acc[0] * i0 + acc[2] * i1 + acc[4] * i2) * (1.f / 3.f) + b2.x;
    float v1 = (acc[1] * i0 + acc[3] * i1 + acc[5] * i2) * (1.f / 3.f) + b2.y;
    v0 = v0 > 0.f ? v0 : 0.f;
    v1 = v1 > 0.f ? v1 : 0.f;
    *(float2*)&out[(size_t)i * OUTC + c] = make_float2(v0, v1);
}

extern "C" void kernel_launch(void* const* d_in, const int* in_sizes, int n_in,
                              void* d_out, int out_size, void* d_ws, size_t ws_size,
                              hipStream_t stream) {
    const float* x    = (const float*)d_in[0];
    const float* Wl1  = (const float*)d_in[1];
    const float* bl1  = (const float*)d_in[2];
    const float* Wr1  = (const float*)d_in[3];
    const float* br1  = (const float*)d_in[4];
    const float* att1 = (const float*)d_in[5];
    const float* bias1= (const float*)d_in[6];
    const float* Wl2  = (const float*)d_in[7];
    const float* bl2  = (const float*)d_in[8];
    const float* Wr2  = (const float*)d_in[9];
    const float* br2  = (const float*)d_in[10];
    const float* att2 = (const float*)d_in[11];
    const float* bias2= (const float*)d_in[12];
    const int*   ei   = (const int*)d_in[13];

    char* ws = (char*)d_ws;
    // Pool layout (bytes), peak 40,004,608:
    //  [0,        7,680,000)  xl1b bf16 [N,192]   \ dead after gather1 ->
    //  [7.68e6,  15,360,000)  xr1b bf16 [N,192]   / xl2 bf16 [N,384] = [0, 15.36e6)
    //  [15.36e6, 23,040,000)  h1b  bf16 [N,192]
    //  [23.04e6, 24,644,104)  CSR: cnt/fill/loc/bsum/rowoff/csrsrc
    //  [24,644,608, 40,004,608)  xr2 bf16 [N,384]
    bf16*  xl1b   = (bf16*)(ws);
    bf16*  xr1b   = (bf16*)(ws + 7680000);
    bf16*  h1b    = (bf16*)(ws + 15360000);
    bf16*  xl2    = (bf16*)(ws);             // alias over xl1b+xr1b
    bf16*  xr2    = (bf16*)(ws + 24644608);
    int*   cnt    = (int*)(ws + 23040000);
    int*   fill   = (int*)(ws + 23120000);
    int*   loc    = (int*)(ws + 23200000);
    int*   bsum   = (int*)(ws + 23280000);
    int*   rowoff = (int*)(ws + 23284096);
    int*   csrsrc = (int*)(ws + 23364104);   // end 24,644,104

    // ---- CSR build (shared by both layers) ----
    hipMemsetAsync(cnt, 0, NN * sizeof(int), stream);
    k_count<<<(EE + 255) / 256, 256, 0, stream>>>(ei, cnt);
    k_scanA<<<NB_SCAN, 256, 0, stream>>>(cnt, loc, bsum);
    k_scanB<<<1, 128, 0, stream>>>(bsum);
    k_scanC<<<NB_SCAN, 256, 0, stream>>>(loc, cnt, bsum, rowoff, fill);
    k_scatter<<<(EE + 255) / 256, 256, 0, stream>>>(ei, fill, csrsrc);

    // ---- layer 1 ----
    gemm1<<<NN / RT, 384, 0, stream>>>(x, Wl1, bl1, Wr1, br1, xl1b, xr1b);
    gather1<<<NN / 4, 256, 0, stream>>>(rowoff, csrsrc, xl1b, xr1b, att1, bias1, h1b);

    // ---- layer 2 (fused across heads) ----
    gemm2<<<NN / RT2, 384, 0, stream>>>(x, h1b, Wl2, bl2, Wr2, br2, xl2, xr2);
    gather2<<<NN / 4, 256, 0, stream>>>(rowoff, csrsrc, xl2, xr2, att2, bias2,
                                        (float*)d_out);
}

// Round 10
// 392.404 us; speedup vs baseline: 3.9907x; 1.1490x over previous
//
#include <hip/hip_runtime.h>
#include <hip/hip_bf16.h>

#define NN 20000
#define EE 320000
#define IN 128
#define HID 64
#define OUTC 128
#define NH 3
#define NEG 0.15f
#define IN2 320
#define HO1 192   // NH*HID
#define HO2 384   // NH*OUTC
#define NB_SCAN 79  // ceil(NN/256)

typedef __hip_bfloat16 bf16;
typedef __attribute__((ext_vector_type(8))) short short8;  // 8 bf16 = 4 VGPR (MFMA A/B frag)
typedef __attribute__((ext_vector_type(4))) float f32x4;   // MFMA C/D frag

__device__ __forceinline__ float bf2f(bf16 v) { return __bfloat162float(v); }
__device__ __forceinline__ bf16 f2bf(float v) { return __float2bfloat16(v); }
__device__ __forceinline__ float lrelu(float s) { return s > 0.f ? s : NEG * s; }

// ---------------- CSR build (by dst) — proven rounds 4/7/8 ----------------
__global__ void k_count(const int* __restrict__ ei, int* __restrict__ cnt) {
    const int e = blockIdx.x * 256 + threadIdx.x;
    if (e < EE) atomicAdd(&cnt[ei[EE + e]], 1);
}

__global__ void k_scanA(const int* __restrict__ cnt, int* __restrict__ loc,
                        int* __restrict__ bsum) {
    __shared__ int sh[256];
    const int t = threadIdx.x;
    const int i = blockIdx.x * 256 + t;
    const int v = (i < NN) ? cnt[i] : 0;
    sh[t] = v; __syncthreads();
    for (int off = 1; off < 256; off <<= 1) {
        const int add = (t >= off) ? sh[t - off] : 0;
        __syncthreads();
        sh[t] += add; __syncthreads();
    }
    if (i < NN) loc[i] = sh[t];
    if (t == 255) bsum[blockIdx.x] = sh[255];
}

__global__ void k_scanB(int* __restrict__ bsum) {
    __shared__ int sh[128];
    const int t = threadIdx.x;
    const int v = (t < NB_SCAN) ? bsum[t] : 0;
    sh[t] = v; __syncthreads();
    for (int off = 1; off < 128; off <<= 1) {
        const int add = (t >= off) ? sh[t - off] : 0;
        __syncthreads();
        sh[t] += add; __syncthreads();
    }
    if (t < NB_SCAN) bsum[t] = sh[t] - v;
}

__global__ void k_scanC(const int* __restrict__ loc, const int* __restrict__ cnt,
                        const int* __restrict__ bsum, int* __restrict__ row_off,
                        int* __restrict__ fill) {
    const int i = blockIdx.x * 256 + threadIdx.x;
    if (i < NN) {
        const int ro = loc[i] - cnt[i] + bsum[blockIdx.x];
        row_off[i] = ro; fill[i] = ro;
    }
    if (i == 0) row_off[NN] = EE;
}

__global__ void k_scatter(const int* __restrict__ ei, int* __restrict__ fill,
                          int* __restrict__ csr_src) {
    const int e = blockIdx.x * 256 + threadIdx.x;
    if (e < EE) {
        const int p = atomicAdd(&fill[ei[EE + e]], 1);
        csr_src[p] = ei[e];
    }
}

// ---------------- pre-pass: bf16 casts / weight transpose ----------------
// xb[i][k] = bf16(x[i][k])
__global__ void k_a2x(const float* __restrict__ x, bf16* __restrict__ xb) {
    const int idx = blockIdx.x * 256 + threadIdx.x;
    if (idx < NN * IN) xb[idx] = f2bf(x[idx]);
}

// Wt[n][k] = bf16( n<NO ? Wl[k][n] : Wr[k][n-NO] )   (k-contiguous rows)
// Wl/Wr are SEPARATE [K,NO] arrays with row stride NO (round-9 bug: used 2*NO).
__global__ void k_wt(const float* __restrict__ Wl, const float* __restrict__ Wr,
                     int K, int NO, bf16* __restrict__ Wt) {
    const int idx = blockIdx.x * 256 + threadIdx.x;
    if (idx >= 2 * NO * K) return;
    const int n = idx / K, k = idx - n * K;
    const float* W = (n < NO) ? Wl : Wr;
    const int nn = (n < NO) ? n : n - NO;
    Wt[idx] = f2bf(W[(size_t)k * NO + nn]);
}

// ---------------- MFMA GEMM (no LDS, L2-staged) ----------------
// out[m][n] = sum_k A[m][k] * W[k][n] + bias[n], A bf16 row-major, Wt[n][k] bf16.
// grid = (M/32, Ntot/128), block = 256 (4 waves).
// wave w: rows [bx*32 + (w>>1)*16, +16), cols [by*128 + (w&1)*64, +64) = 4 N-tiles.
// Layouts (gfx950, HW-verified): A[m=lane&15][k=quad*8+j]; B[n=lane&15][k=quad*8+j];
// D col=lane&15, row=quad*4+reg.
template <int K>
__launch_bounds__(256)
__global__ void gemm_mfma(const bf16* __restrict__ A0, int As0,   // source for k<128
                          const bf16* __restrict__ A1, int As1,   // source for k>=128 (index k-128)
                          const bf16* __restrict__ Wt,
                          const float* __restrict__ bl, const float* __restrict__ br,
                          int NO, bf16* __restrict__ outl, bf16* __restrict__ outr) {
    const int w = threadIdx.x >> 6;
    const int lane = threadIdx.x & 63;
    const int quad = lane >> 4, l15 = lane & 15;
    const int m0 = blockIdx.x * 32 + (w >> 1) * 16;
    const int n0 = blockIdx.y * 128 + (w & 1) * 64;

    f32x4 acc[4];
#pragma unroll
    for (int nt = 0; nt < 4; ++nt) {
        const int col = n0 + nt * 16 + l15;
        const float b = (col < NO) ? bl[col] : br[col - NO];
        acc[nt] = (f32x4){b, b, b, b};
    }
    const int am = m0 + l15;
    for (int ks = 0; ks < K; ks += 32) {
        const bf16* ap = (ks < 128) ? (A0 + (size_t)am * As0 + ks)
                                    : (A1 + (size_t)am * As1 + (ks - 128));
        const short8 af = *(const short8*)(ap + quad * 8);
#pragma unroll
        for (int nt = 0; nt < 4; ++nt) {
            const short8 bf = *(const short8*)(Wt + (size_t)(n0 + nt * 16 + l15) * K + ks + quad * 8);
            acc[nt] = __builtin_amdgcn_mfma_f32_16x16x32_bf16(af, bf, acc[nt], 0, 0, 0);
        }
    }
#pragma unroll
    for (int nt = 0; nt < 4; ++nt) {
        const int col = n0 + nt * 16 + l15;
        bf16* o = (col < NO) ? (outl + col) : (outr + (col - NO));
#pragma unroll
        for (int r = 0; r < 4; ++r) {
            const int row = m0 + quad * 4 + r;
            o[(size_t)row * NO] = f2bf(acc[nt][r]);
        }
    }
}

// ---------------- gather1 (unchanged from round 8, proven) ----------------
__global__ void gather1(const int* __restrict__ row_off, const int* __restrict__ csr_src,
                        const bf16* __restrict__ xl, const bf16* __restrict__ xr,
                        const float* __restrict__ att, const float* __restrict__ bias,
                        bf16* __restrict__ h1) {
    const int i = (blockIdx.x * blockDim.x + threadIdx.x) >> 6;
    const int lane = threadIdx.x & 63;
    if (i >= NN) return;
    const float rv0 = bf2f(xr[(size_t)i * HO1 + lane]);
    const float rv1 = bf2f(xr[(size_t)i * HO1 + 64 + lane]);
    const float rv2 = bf2f(xr[(size_t)i * HO1 + 128 + lane]);
    const float av0 = att[lane], av1 = att[64 + lane], av2 = att[128 + lane];
    int k = row_off[i];
    const int e = row_off[i + 1];
    float a0 = 0.f, a1 = 0.f, a2 = 0.f, d0 = 0.f, d1 = 0.f, d2 = 0.f;
    while (k < e) {
        const int batch = min(64, e - k);
        const int jv = (lane < batch) ? csr_src[k + lane] : 0;
        int m = 0;
        for (; m + 1 < batch; m += 2) {
            const int ja = __shfl(jv, m, 64);
            const int jb = __shfl(jv, m + 1, 64);
            const float lA0 = bf2f(xl[(size_t)ja * HO1 + lane]);
            const float lA1 = bf2f(xl[(size_t)ja * HO1 + 64 + lane]);
            const float lA2 = bf2f(xl[(size_t)ja * HO1 + 128 + lane]);
            const float lB0 = bf2f(xl[(size_t)jb * HO1 + lane]);
            const float lB1 = bf2f(xl[(size_t)jb * HO1 + 64 + lane]);
            const float lB2 = bf2f(xl[(size_t)jb * HO1 + 128 + lane]);
            float pA0 = lrelu(lA0 + rv0) * av0;
            float pA1 = lrelu(lA1 + rv1) * av1;
            float pA2 = lrelu(lA2 + rv2) * av2;
            float pB0 = lrelu(lB0 + rv0) * av0;
            float pB1 = lrelu(lB1 + rv1) * av1;
            float pB2 = lrelu(lB2 + rv2) * av2;
#pragma unroll
            for (int off = 32; off > 0; off >>= 1) {
                pA0 += __shfl_xor(pA0, off, 64);
                pA1 += __shfl_xor(pA1, off, 64);
                pA2 += __shfl_xor(pA2, off, 64);
                pB0 += __shfl_xor(pB0, off, 64);
                pB1 += __shfl_xor(pB1, off, 64);
                pB2 += __shfl_xor(pB2, off, 64);
            }
            const float eA0 = __expf(pA0), eA1 = __expf(pA1), eA2 = __expf(pA2);
            const float eB0 = __expf(pB0), eB1 = __expf(pB1), eB2 = __expf(pB2);
            a0 += eA0 * lA0 + eB0 * lB0; d0 += eA0 + eB0;
            a1 += eA1 * lA1 + eB1 * lB1; d1 += eA1 + eB1;
            a2 += eA2 * lA2 + eB2 * lB2; d2 += eA2 + eB2;
        }
        if (m < batch) {
            const int j = __shfl(jv, m, 64);
            const float l0 = bf2f(xl[(size_t)j * HO1 + lane]);
            const float l1 = bf2f(xl[(size_t)j * HO1 + 64 + lane]);
            const float l2 = bf2f(xl[(size_t)j * HO1 + 128 + lane]);
            float p0 = lrelu(l0 + rv0) * av0;
            float p1 = lrelu(l1 + rv1) * av1;
            float p2 = lrelu(l2 + rv2) * av2;
#pragma unroll
            for (int off = 32; off > 0; off >>= 1) {
                p0 += __shfl_xor(p0, off, 64);
                p1 += __shfl_xor(p1, off, 64);
                p2 += __shfl_xor(p2, off, 64);
            }
            const float e0 = __expf(p0), e1 = __expf(p1), e2 = __expf(p2);
            a0 += e0 * l0; d0 += e0;
            a1 += e1 * l1; d1 += e1;
            a2 += e2 * l2; d2 += e2;
        }
        k += batch;
    }
    const float o0 = a0 / (d0 + 1e-16f) + bias[lane];
    const float o1 = a1 / (d1 + 1e-16f) + bias[64 + lane];
    const float o2 = a2 / (d2 + 1e-16f) + bias[128 + lane];
    h1[(size_t)i * HO1 + lane]       = f2bf(o0 > 0.f ? o0 : 0.f);
    h1[(size_t)i * HO1 + 64 + lane]  = f2bf(o1 > 0.f ? o1 : 0.f);
    h1[(size_t)i * HO1 + 128 + lane] = f2bf(o2 > 0.f ? o2 : 0.f);
}

// ---------------- gather2 (unchanged from round 8, proven) ----------------
__global__ void gather2(const int* __restrict__ row_off, const int* __restrict__ csr_src,
                        const bf16* __restrict__ xl2, const bf16* __restrict__ xr2,
                        const float* __restrict__ att2, const float* __restrict__ bias2,
                        float* __restrict__ out) {
    const int i = (blockIdx.x * blockDim.x + threadIdx.x) >> 6;
    const int lane = threadIdx.x & 63;
    if (i >= NN) return;
    const int c = lane * 2;
    float rv[6], av[6];
#pragma unroll
    for (int h = 0; h < NH; ++h) {
        const __hip_bfloat162 r2 = *(const __hip_bfloat162*)&xr2[(size_t)i * HO2 + h * OUTC + c];
        rv[2 * h] = bf2f(r2.x); rv[2 * h + 1] = bf2f(r2.y);
        const float2 a2 = *(const float2*)&att2[h * OUTC + c];
        av[2 * h] = a2.x; av[2 * h + 1] = a2.y;
    }
    float acc[6] = {0.f, 0.f, 0.f, 0.f, 0.f, 0.f};
    float den[3] = {0.f, 0.f, 0.f};
    int k = row_off[i];
    const int e = row_off[i + 1];
    while (k < e) {
        const int batch = min(64, e - k);
        const int jv = (lane < batch) ? csr_src[k + lane] : 0;
        int m = 0;
        for (; m + 1 < batch; m += 2) {
            const int ja = __shfl(jv, m, 64);
            const int jb = __shfl(jv, m + 1, 64);
            float lA[6], lB[6];
#pragma unroll
            for (int h = 0; h < NH; ++h) {
                const __hip_bfloat162 A = *(const __hip_bfloat162*)&xl2[(size_t)ja * HO2 + h * OUTC + c];
                const __hip_bfloat162 B = *(const __hip_bfloat162*)&xl2[(size_t)jb * HO2 + h * OUTC + c];
                lA[2 * h] = bf2f(A.x); lA[2 * h + 1] = bf2f(A.y);
                lB[2 * h] = bf2f(B.x); lB[2 * h + 1] = bf2f(B.y);
            }
            float pA0 = lrelu(lA[0] + rv[0]) * av[0] + lrelu(lA[1] + rv[1]) * av[1];
            float pA1 = lrelu(lA[2] + rv[2]) * av[2] + lrelu(lA[3] + rv[3]) * av[3];
            float pA2 = lrelu(lA[4] + rv[4]) * av[4] + lrelu(lA[5] + rv[5]) * av[5];
            float pB0 = lrelu(lB[0] + rv[0]) * av[0] + lrelu(lB[1] + rv[1]) * av[1];
            float pB1 = lrelu(lB[2] + rv[2]) * av[2] + lrelu(lB[3] + rv[3]) * av[3];
            float pB2 = lrelu(lB[4] + rv[4]) * av[4] + lrelu(lB[5] + rv[5]) * av[5];
#pragma unroll
            for (int off = 32; off > 0; off >>= 1) {
                pA0 += __shfl_xor(pA0, off, 64);
                pA1 += __shfl_xor(pA1, off, 64);
                pA2 += __shfl_xor(pA2, off, 64);
                pB0 += __shfl_xor(pB0, off, 64);
                pB1 += __shfl_xor(pB1, off, 64);
                pB2 += __shfl_xor(pB2, off, 64);
            }
            const float eA0 = __expf(pA0), eA1 = __expf(pA1), eA2 = __expf(pA2);
            const float eB0 = __expf(pB0), eB1 = __expf(pB1), eB2 = __expf(pB2);
            acc[0] += eA0 * lA[0] + eB0 * lB[0];
            acc[1] += eA0 * lA[1] + eB0 * lB[1];
            acc[2] += eA1 * lA[2] + eB1 * lB[2];
            acc[3] += eA1 * lA[3] + eB1 * lB[3];
            acc[4] += eA2 * lA[4] + eB2 * lB[4];
            acc[5] += eA2 * lA[5] + eB2 * lB[5];
            den[0] += eA0 + eB0; den[1] += eA1 + eB1; den[2] += eA2 + eB2;
        }
        if (m < batch) {
            const int j = __shfl(jv, m, 64);
            float lv[6];
#pragma unroll
            for (int h = 0; h < NH; ++h) {
                const __hip_bfloat162 A = *(const __hip_bfloat162*)&xl2[(size_t)j * HO2 + h * OUTC + c];
                lv[2 * h] = bf2f(A.x); lv[2 * h + 1] = bf2f(A.y);
            }
            float p0 = lrelu(lv[0] + rv[0]) * av[0] + lrelu(lv[1] + rv[1]) * av[1];
            float p1 = lrelu(lv[2] + rv[2]) * av[2] + lrelu(lv[3] + rv[3]) * av[3];
            float p2 = lrelu(lv[4] + rv[4]) * av[4] + lrelu(lv[5] + rv[5]) * av[5];
#pragma unroll
            for (int off = 32; off > 0; off >>= 1) {
                p0 += __shfl_xor(p0, off, 64);
                p1 += __shfl_xor(p1, off, 64);
                p2 += __shfl_xor(p2, off, 64);
            }
            const float e0 = __expf(p0), e1 = __expf(p1), e2 = __expf(p2);
            acc[0] += e0 * lv[0]; acc[1] += e0 * lv[1];
            acc[2] += e1 * lv[2]; acc[3] += e1 * lv[3];
            acc[4] += e2 * lv[4]; acc[5] += e2 * lv[5];
            den[0] += e0; den[1] += e1; den[2] += e2;
        }
        k += batch;
    }
    const float i0 = 1.f / (den[0] + 1e-16f);
    const float i1 = 1.f / (den[1] + 1e-16f);
    const float i2 = 1.f / (den[2] + 1e-16f);
    const float2 b2 = *(const float2*)&bias2[c];
    float v0 = (acc[0] * i0 + acc[2] * i1 + acc[4] * i2) * (1.f / 3.f) + b2.x;
    float v1 = (acc[1] * i0 + acc[3] * i1 + acc[5] * i2) * (1.f / 3.f) + b2.y;
    v0 = v0 > 0.f ? v0 : 0.f;
    v1 = v1 > 0.f ? v1 : 0.f;
    *(float2*)&out[(size_t)i * OUTC + c] = make_float2(v0, v1);
}

extern "C" void kernel_launch(void* const* d_in, const int* in_sizes, int n_in,
                              void* d_out, int out_size, void* d_ws, size_t ws_size,
                              hipStream_t stream) {
    const float* x    = (const float*)d_in[0];
    const float* Wl1  = (const float*)d_in[1];
    const float* bl1  = (const float*)d_in[2];
    const float* Wr1  = (const float*)d_in[3];
    const float* br1  = (const float*)d_in[4];
    const float* att1 = (const float*)d_in[5];
    const float* bias1= (const float*)d_in[6];
    const float* Wl2  = (const float*)d_in[7];
    const float* bl2  = (const float*)d_in[8];
    const float* Wr2  = (const float*)d_in[9];
    const float* br2  = (const float*)d_in[10];
    const float* att2 = (const float*)d_in[11];
    const float* bias2= (const float*)d_in[12];
    const int*   ei   = (const int*)d_in[13];

    char* ws = (char*)d_ws;
    // Pool layout (bytes), peak 45,713,936:
    //  [0,         5,120,000)  xb   bf16 [N,128]
    //  [5.12e6,   12,800,000)  h1b  bf16 [N,192]
    //  [12.8e6,   20,480,000)  xl1b bf16 [N,192]  \ dead after gather1 ->
    //  [20.48e6,  28,160,000)  xr1b bf16 [N,192]  /  xl2 bf16 [N,384] = [12.8e6, 28.16e6)
    //  [28.16e6,  43,520,000)  xr2  bf16 [N,384]
    //  [43.52e6,  45,124,104)  CSR: cnt/fill/loc/bsum/rowoff/csrsrc
    //  [45,124,112, 45,222,416)  Wt1 bf16 [384][128]
    //  [45,222,416, 45,713,936)  Wt2 bf16 [768][320]
    bf16*  xb     = (bf16*)(ws);
    bf16*  h1b    = (bf16*)(ws + 5120000);
    bf16*  xl1b   = (bf16*)(ws + 12800000);
    bf16*  xr1b   = (bf16*)(ws + 20480000);
    bf16*  xl2    = (bf16*)(ws + 12800000);   // alias over xl1b+xr1b
    bf16*  xr2    = (bf16*)(ws + 28160000);
    int*   cnt    = (int*)(ws + 43520000);
    int*   fill   = (int*)(ws + 43600000);
    int*   loc    = (int*)(ws + 43680000);
    int*   bsum   = (int*)(ws + 43760000);
    int*   rowoff = (int*)(ws + 43764096);
    int*   csrsrc = (int*)(ws + 43844104);    // +1,280,000 -> 45,124,104
    bf16*  Wt1    = (bf16*)(ws + 45124112);
    bf16*  Wt2    = (bf16*)(ws + 45222416);

    // ---- pre-pass: casts + weight transposes ----
    k_a2x<<<(NN * IN + 255) / 256, 256, 0, stream>>>(x, xb);
    k_wt<<<(HO2 * IN + 255) / 256, 256, 0, stream>>>(Wl1, Wr1, IN, HO1, Wt1);      // 384x128
    k_wt<<<(2 * HO2 * IN2 + 255) / 256, 256, 0, stream>>>(Wl2, Wr2, IN2, HO2, Wt2); // 768x320

    // ---- CSR build (shared by both layers) ----
    hipMemsetAsync(cnt, 0, NN * sizeof(int), stream);
    k_count<<<(EE + 255) / 256, 256, 0, stream>>>(ei, cnt);
    k_scanA<<<NB_SCAN, 256, 0, stream>>>(cnt, loc, bsum);
    k_scanB<<<1, 128, 0, stream>>>(bsum);
    k_scanC<<<NB_SCAN, 256, 0, stream>>>(loc, cnt, bsum, rowoff, fill);
    k_scatter<<<(EE + 255) / 256, 256, 0, stream>>>(ei, fill, csrsrc);

    // ---- layer 1 ----
    gemm_mfma<IN><<<dim3(NN / 32, HO2 / 128), 256, 0, stream>>>(
        xb, IN, (const bf16*)nullptr, 0, Wt1, bl1, br1, HO1, xl1b, xr1b);
    gather1<<<NN / 4, 256, 0, stream>>>(rowoff, csrsrc, xl1b, xr1b, att1, bias1, h1b);

    // ---- layer 2 ----
    gemm_mfma<IN2><<<dim3(NN / 32, 2 * HO2 / 128), 256, 0, stream>>>(
        xb, IN, h1b, HO1, Wt2, bl2, br2, HO2, xl2, xr2);
    gather2<<<NN / 4, 256, 0, stream>>>(rowoff, csrsrc, xl2, xr2, att2, bias2,
                                        (float*)d_out);
}

// Round 11
// 358.160 us; speedup vs baseline: 4.3722x; 1.0956x over previous
//
#include <hip/hip_runtime.h>
#include <hip/hip_bf16.h>

#define NN 20000
#define EE 320000
#define IN 128
#define HID 64
#define OUTC 128
#define NH 3
#define NEG 0.15f
#define IN2 320
#define HO1 192   // NH*HID
#define HO2 384   // NH*OUTC
#define NB_SCAN 79  // ceil(NN/256)
#define GRIDM 313   // ceil(NN/64)

typedef __hip_bfloat16 bf16;
typedef __attribute__((ext_vector_type(8))) short short8;  // 8 bf16 = 4 VGPR (MFMA A/B frag)
typedef __attribute__((ext_vector_type(4))) float f32x4;   // MFMA C/D frag

__device__ __forceinline__ float bf2f(bf16 v) { return __bfloat162float(v); }
__device__ __forceinline__ bf16 f2bf(float v) { return __float2bfloat16(v); }
__device__ __forceinline__ float lrelu(float s) { return s > 0.f ? s : NEG * s; }

// ---------------- CSR build (by dst) — proven rounds 4/7/8/10 ----------------
__global__ void k_count(const int* __restrict__ ei, int* __restrict__ cnt) {
    const int e = blockIdx.x * 256 + threadIdx.x;
    if (e < EE) atomicAdd(&cnt[ei[EE + e]], 1);
}

__global__ void k_scanA(const int* __restrict__ cnt, int* __restrict__ loc,
                        int* __restrict__ bsum) {
    __shared__ int sh[256];
    const int t = threadIdx.x;
    const int i = blockIdx.x * 256 + t;
    const int v = (i < NN) ? cnt[i] : 0;
    sh[t] = v; __syncthreads();
    for (int off = 1; off < 256; off <<= 1) {
        const int add = (t >= off) ? sh[t - off] : 0;
        __syncthreads();
        sh[t] += add; __syncthreads();
    }
    if (i < NN) loc[i] = sh[t];
    if (t == 255) bsum[blockIdx.x] = sh[255];
}

__global__ void k_scanB(int* __restrict__ bsum) {
    __shared__ int sh[128];
    const int t = threadIdx.x;
    const int v = (t < NB_SCAN) ? bsum[t] : 0;
    sh[t] = v; __syncthreads();
    for (int off = 1; off < 128; off <<= 1) {
        const int add = (t >= off) ? sh[t - off] : 0;
        __syncthreads();
        sh[t] += add; __syncthreads();
    }
    if (t < NB_SCAN) bsum[t] = sh[t] - v;
}

__global__ void k_scanC(const int* __restrict__ loc, const int* __restrict__ cnt,
                        const int* __restrict__ bsum, int* __restrict__ row_off,
                        int* __restrict__ fill) {
    const int i = blockIdx.x * 256 + threadIdx.x;
    if (i < NN) {
        const int ro = loc[i] - cnt[i] + bsum[blockIdx.x];
        row_off[i] = ro; fill[i] = ro;
    }
    if (i == 0) row_off[NN] = EE;
}

__global__ void k_scatter(const int* __restrict__ ei, int* __restrict__ fill,
                          int* __restrict__ csr_src) {
    const int e = blockIdx.x * 256 + threadIdx.x;
    if (e < EE) {
        const int p = atomicAdd(&fill[ei[EE + e]], 1);
        csr_src[p] = ei[e];
    }
}

// ---------------- pre-pass: bf16 casts / weight transpose ----------------
__global__ void k_a2x(const float* __restrict__ x, bf16* __restrict__ xb) {
    const int idx = blockIdx.x * 256 + threadIdx.x;
    if (idx < NN * IN) xb[idx] = f2bf(x[idx]);
}

// Wt[n][k] = bf16( n<NO ? Wl[k][n] : Wr[k][n-NO] ), Wl/Wr [K,NO] row stride NO
__global__ void k_wt(const float* __restrict__ Wl, const float* __restrict__ Wr,
                     int K, int NO, bf16* __restrict__ Wt) {
    const int idx = blockIdx.x * 256 + threadIdx.x;
    if (idx >= 2 * NO * K) return;
    const int n = idx / K, k = idx - n * K;
    const float* W = (n < NO) ? Wl : Wr;
    const int nn = (n < NO) ? n : n - NO;
    Wt[idx] = f2bf(W[(size_t)k * NO + nn]);
}

// ---------------- MFMA GEMM v2: 32x64/wave, explicit 1-step prefetch ----------
// grid = (ceil(M/64), Ntot/128), block = 256 (4 waves).
// wave w: rows [bx*64 + (w>>1)*32, +32) (2 m-frags), cols [by*128 + (w&1)*64, +64) (4 n-frags).
// Layouts (HW-verified, round 10 passed): A[m=lane&15][k=quad*8+j];
// B[n=lane&15][k=quad*8+j]; D col=lane&15, row=quad*4+reg.
template <int K>
__launch_bounds__(256)
__global__ void gemm_mfma(const bf16* __restrict__ A0, int As0,   // k < 128
                          const bf16* __restrict__ A1, int As1,   // k >= 128 (index k-128)
                          const bf16* __restrict__ Wt,
                          const float* __restrict__ bl, const float* __restrict__ br,
                          int NO, bf16* __restrict__ outl, bf16* __restrict__ outr) {
    const int w = threadIdx.x >> 6;
    const int lane = threadIdx.x & 63;
    const int quad = lane >> 4, l15 = lane & 15;
    const int m0 = blockIdx.x * 64 + (w >> 1) * 32;
    const int n0 = blockIdx.y * 128 + (w & 1) * 64;

    int am0 = m0 + l15;      if (am0 >= NN) am0 = NN - 1;   // clamp: loads stay in ws
    int am1 = m0 + 16 + l15; if (am1 >= NN) am1 = NN - 1;
    const bf16* wp = Wt + (size_t)(n0 + l15) * K + quad * 8;

    f32x4 acc[2][4];
#pragma unroll
    for (int nt = 0; nt < 4; ++nt) {
        const int col = n0 + nt * 16 + l15;
        const float b = (col < NO) ? bl[col] : br[col - NO];
        acc[0][nt] = (f32x4){b, b, b, b};
        acc[1][nt] = (f32x4){b, b, b, b};
    }

    // current fragments (K-step 0)
    short8 ca0, ca1, cb[4];
    {
        const bf16* a0p = A0 + (size_t)am0 * As0 + quad * 8;
        const bf16* a1p = A0 + (size_t)am1 * As0 + quad * 8;
        ca0 = *(const short8*)a0p;
        ca1 = *(const short8*)a1p;
#pragma unroll
        for (int nt = 0; nt < 4; ++nt)
            cb[nt] = *(const short8*)(wp + (size_t)nt * 16 * K);
    }

#pragma unroll
    for (int ks = 0; ks < K; ks += 32) {
        short8 na0 = {}, na1 = {}, nb[4] = {};
        if (ks + 32 < K) {                       // compile-time per unrolled instance
            const int nks = ks + 32;
            const bf16* a0p = (K <= 128 || nks < 128)
                ? (A0 + (size_t)am0 * As0 + nks) : (A1 + (size_t)am0 * As1 + (nks - 128));
            const bf16* a1p = (K <= 128 || nks < 128)
                ? (A0 + (size_t)am1 * As0 + nks) : (A1 + (size_t)am1 * As1 + (nks - 128));
            na0 = *(const short8*)(a0p + quad * 8);
            na1 = *(const short8*)(a1p + quad * 8);
#pragma unroll
            for (int nt = 0; nt < 4; ++nt)
                nb[nt] = *(const short8*)(wp + (size_t)nt * 16 * K + nks);
        }
#pragma unroll
        for (int nt = 0; nt < 4; ++nt) {
            acc[0][nt] = __builtin_amdgcn_mfma_f32_16x16x32_bf16(ca0, cb[nt], acc[0][nt], 0, 0, 0);
            acc[1][nt] = __builtin_amdgcn_mfma_f32_16x16x32_bf16(ca1, cb[nt], acc[1][nt], 0, 0, 0);
        }
        ca0 = na0; ca1 = na1;
#pragma unroll
        for (int nt = 0; nt < 4; ++nt) cb[nt] = nb[nt];
    }

#pragma unroll
    for (int mt = 0; mt < 2; ++mt)
#pragma unroll
    for (int nt = 0; nt < 4; ++nt) {
        const int col = n0 + nt * 16 + l15;
        bf16* o = (col < NO) ? (outl + col) : (outr + (col - NO));
#pragma unroll
        for (int r = 0; r < 4; ++r) {
            const int row = m0 + mt * 16 + quad * 4 + r;
            if (row < NN) o[(size_t)row * NO] = f2bf(acc[mt][nt][r]);
        }
    }
}

// ---------------- gather1 (unchanged, proven) ----------------
__global__ void gather1(const int* __restrict__ row_off, const int* __restrict__ csr_src,
                        const bf16* __restrict__ xl, const bf16* __restrict__ xr,
                        const float* __restrict__ att, const float* __restrict__ bias,
                        bf16* __restrict__ h1) {
    const int i = (blockIdx.x * blockDim.x + threadIdx.x) >> 6;
    const int lane = threadIdx.x & 63;
    if (i >= NN) return;
    const float rv0 = bf2f(xr[(size_t)i * HO1 + lane]);
    const float rv1 = bf2f(xr[(size_t)i * HO1 + 64 + lane]);
    const float rv2 = bf2f(xr[(size_t)i * HO1 + 128 + lane]);
    const float av0 = att[lane], av1 = att[64 + lane], av2 = att[128 + lane];
    int k = row_off[i];
    const int e = row_off[i + 1];
    float a0 = 0.f, a1 = 0.f, a2 = 0.f, d0 = 0.f, d1 = 0.f, d2 = 0.f;
    while (k < e) {
        const int batch = min(64, e - k);
        const int jv = (lane < batch) ? csr_src[k + lane] : 0;
        int m = 0;
        for (; m + 1 < batch; m += 2) {
            const int ja = __shfl(jv, m, 64);
            const int jb = __shfl(jv, m + 1, 64);
            const float lA0 = bf2f(xl[(size_t)ja * HO1 + lane]);
            const float lA1 = bf2f(xl[(size_t)ja * HO1 + 64 + lane]);
            const float lA2 = bf2f(xl[(size_t)ja * HO1 + 128 + lane]);
            const float lB0 = bf2f(xl[(size_t)jb * HO1 + lane]);
            const float lB1 = bf2f(xl[(size_t)jb * HO1 + 64 + lane]);
            const float lB2 = bf2f(xl[(size_t)jb * HO1 + 128 + lane]);
            float pA0 = lrelu(lA0 + rv0) * av0;
            float pA1 = lrelu(lA1 + rv1) * av1;
            float pA2 = lrelu(lA2 + rv2) * av2;
            float pB0 = lrelu(lB0 + rv0) * av0;
            float pB1 = lrelu(lB1 + rv1) * av1;
            float pB2 = lrelu(lB2 + rv2) * av2;
#pragma unroll
            for (int off = 32; off > 0; off >>= 1) {
                pA0 += __shfl_xor(pA0, off, 64);
                pA1 += __shfl_xor(pA1, off, 64);
                pA2 += __shfl_xor(pA2, off, 64);
                pB0 += __shfl_xor(pB0, off, 64);
                pB1 += __shfl_xor(pB1, off, 64);
                pB2 += __shfl_xor(pB2, off, 64);
            }
            const float eA0 = __expf(pA0), eA1 = __expf(pA1), eA2 = __expf(pA2);
            const float eB0 = __expf(pB0), eB1 = __expf(pB1), eB2 = __expf(pB2);
            a0 += eA0 * lA0 + eB0 * lB0; d0 += eA0 + eB0;
            a1 += eA1 * lA1 + eB1 * lB1; d1 += eA1 + eB1;
            a2 += eA2 * lA2 + eB2 * lB2; d2 += eA2 + eB2;
        }
        if (m < batch) {
            const int j = __shfl(jv, m, 64);
            const float l0 = bf2f(xl[(size_t)j * HO1 + lane]);
            const float l1 = bf2f(xl[(size_t)j * HO1 + 64 + lane]);
            const float l2 = bf2f(xl[(size_t)j * HO1 + 128 + lane]);
            float p0 = lrelu(l0 + rv0) * av0;
            float p1 = lrelu(l1 + rv1) * av1;
            float p2 = lrelu(l2 + rv2) * av2;
#pragma unroll
            for (int off = 32; off > 0; off >>= 1) {
                p0 += __shfl_xor(p0, off, 64);
                p1 += __shfl_xor(p1, off, 64);
                p2 += __shfl_xor(p2, off, 64);
            }
            const float e0 = __expf(p0), e1 = __expf(p1), e2 = __expf(p2);
            a0 += e0 * l0; d0 += e0;
            a1 += e1 * l1; d1 += e1;
            a2 += e2 * l2; d2 += e2;
        }
        k += batch;
    }
    const float o0 = a0 / (d0 + 1e-16f) + bias[lane];
    const float o1 = a1 / (d1 + 1e-16f) + bias[64 + lane];
    const float o2 = a2 / (d2 + 1e-16f) + bias[128 + lane];
    h1[(size_t)i * HO1 + lane]       = f2bf(o0 > 0.f ? o0 : 0.f);
    h1[(size_t)i * HO1 + 64 + lane]  = f2bf(o1 > 0.f ? o1 : 0.f);
    h1[(size_t)i * HO1 + 128 + lane] = f2bf(o2 > 0.f ? o2 : 0.f);
}

// ---------------- gather2 (unchanged, proven) ----------------
__global__ void gather2(const int* __restrict__ row_off, const int* __restrict__ csr_src,
                        const bf16* __restrict__ xl2, const bf16* __restrict__ xr2,
                        const float* __restrict__ att2, const float* __restrict__ bias2,
                        float* __restrict__ out) {
    const int i = (blockIdx.x * blockDim.x + threadIdx.x) >> 6;
    const int lane = threadIdx.x & 63;
    if (i >= NN) return;
    const int c = lane * 2;
    float rv[6], av[6];
#pragma unroll
    for (int h = 0; h < NH; ++h) {
        const __hip_bfloat162 r2 = *(const __hip_bfloat162*)&xr2[(size_t)i * HO2 + h * OUTC + c];
        rv[2 * h] = bf2f(r2.x); rv[2 * h + 1] = bf2f(r2.y);
        const float2 a2 = *(const float2*)&att2[h * OUTC + c];
        av[2 * h] = a2.x; av[2 * h + 1] = a2.y;
    }
    float acc[6] = {0.f, 0.f, 0.f, 0.f, 0.f, 0.f};
    float den[3] = {0.f, 0.f, 0.f};
    int k = row_off[i];
    const int e = row_off[i + 1];
    while (k < e) {
        const int batch = min(64, e - k);
        const int jv = (lane < batch) ? csr_src[k + lane] : 0;
        int m = 0;
        for (; m + 1 < batch; m += 2) {
            const int ja = __shfl(jv, m, 64);
            const int jb = __shfl(jv, m + 1, 64);
            float lA[6], lB[6];
#pragma unroll
            for (int h = 0; h < NH; ++h) {
                const __hip_bfloat162 A = *(const __hip_bfloat162*)&xl2[(size_t)ja * HO2 + h * OUTC + c];
                const __hip_bfloat162 B = *(const __hip_bfloat162*)&xl2[(size_t)jb * HO2 + h * OUTC + c];
                lA[2 * h] = bf2f(A.x); lA[2 * h + 1] = bf2f(A.y);
                lB[2 * h] = bf2f(B.x); lB[2 * h + 1] = bf2f(B.y);
            }
            float pA0 = lrelu(lA[0] + rv[0]) * av[0] + lrelu(lA[1] + rv[1]) * av[1];
            float pA1 = lrelu(lA[2] + rv[2]) * av[2] + lrelu(lA[3] + rv[3]) * av[3];
            float pA2 = lrelu(lA[4] + rv[4]) * av[4] + lrelu(lA[5] + rv[5]) * av[5];
            float pB0 = lrelu(lB[0] + rv[0]) * av[0] + lrelu(lB[1] + rv[1]) * av[1];
            float pB1 = lrelu(lB[2] + rv[2]) * av[2] + lrelu(lB[3] + rv[3]) * av[3];
            float pB2 = lrelu(lB[4] + rv[4]) * av[4] + lrelu(lB[5] + rv[5]) * av[5];
#pragma unroll
            for (int off = 32; off > 0; off >>= 1) {
                pA0 += __shfl_xor(pA0, off, 64);
                pA1 += __shfl_xor(pA1, off, 64);
                pA2 += __shfl_xor(pA2, off, 64);
                pB0 += __shfl_xor(pB0, off, 64);
                pB1 += __shfl_xor(pB1, off, 64);
                pB2 += __shfl_xor(pB2, off, 64);
            }
            const float eA0 = __expf(pA0), eA1 = __expf(pA1), eA2 = __expf(pA2);
            const float eB0 = __expf(pB0), eB1 = __expf(pB1), eB2 = __expf(pB2);
            acc[0] += eA0 * lA[0] + eB0 * lB[0];
            acc[1] += eA0 * lA[1] + eB0 * lB[1];
            acc[2] += eA1 * lA[2] + eB1 * lB[2];
            acc[3] += eA1 * lA[3] + eB1 * lB[3];
            acc[4] += eA2 * lA[4] + eB2 * lB[4];
            acc[5] += eA2 * lA[5] + eB2 * lB[5];
            den[0] += eA0 + eB0; den[1] += eA1 + eB1; den[2] += eA2 + eB2;
        }
        if (m < batch) {
            const int j = __shfl(jv, m, 64);
            float lv[6];
#pragma unroll
            for (int h = 0; h < NH; ++h) {
                const __hip_bfloat162 A = *(const __hip_bfloat162*)&xl2[(size_t)j * HO2 + h * OUTC + c];
                lv[2 * h] = bf2f(A.x); lv[2 * h + 1] = bf2f(A.y);
            }
            float p0 = lrelu(lv[0] + rv[0]) * av[0] + lrelu(lv[1] + rv[1]) * av[1];
            float p1 = lrelu(lv[2] + rv[2]) * av[2] + lrelu(lv[3] + rv[3]) * av[3];
            float p2 = lrelu(lv[4] + rv[4]) * av[4] + lrelu(lv[5] + rv[5]) * av[5];
#pragma unroll
            for (int off = 32; off > 0; off >>= 1) {
                p0 += __shfl_xor(p0, off, 64);
                p1 += __shfl_xor(p1, off, 64);
                p2 += __shfl_xor(p2, off, 64);
            }
            const float e0 = __expf(p0), e1 = __expf(p1), e2 = __expf(p2);
            acc[0] += e0 * lv[0]; acc[1] += e0 * lv[1];
            acc[2] += e1 * lv[2]; acc[3] += e1 * lv[3];
            acc[4] += e2 * lv[4]; acc[5] += e2 * lv[5];
            den[0] += e0; den[1] += e1; den[2] += e2;
        }
        k += batch;
    }
    const float i0 = 1.f / (den[0] + 1e-16f);
    const float i1 = 1.f / (den[1] + 1e-16f);
    const float i2 = 1.f / (den[2] + 1e-16f);
    const float2 b2 = *(const float2*)&bias2[c];
    float v0 = (acc[0] * i0 + acc[2] * i1 + acc[4] * i2) * (1.f / 3.f) + b2.x;
    float v1 = (acc[1] * i0 + acc[3] * i1 + acc[5] * i2) * (1.f / 3.f) + b2.y;
    v0 = v0 > 0.f ? v0 : 0.f;
    v1 = v1 > 0.f ? v1 : 0.f;
    *(float2*)&out[(size_t)i * OUTC + c] = make_float2(v0, v1);
}

extern "C" void kernel_launch(void* const* d_in, const int* in_sizes, int n_in,
                              void* d_out, int out_size, void* d_ws, size_t ws_size,
                              hipStream_t stream) {
    const float* x    = (const float*)d_in[0];
    const float* Wl1  = (const float*)d_in[1];
    const float* bl1  = (const float*)d_in[2];
    const float* Wr1  = (const float*)d_in[3];
    const float* br1  = (const float*)d_in[4];
    const float* att1 = (const float*)d_in[5];
    const float* bias1= (const float*)d_in[6];
    const float* Wl2  = (const float*)d_in[7];
    const float* bl2  = (const float*)d_in[8];
    const float* Wr2  = (const float*)d_in[9];
    const float* br2  = (const float*)d_in[10];
    const float* att2 = (const float*)d_in[11];
    const float* bias2= (const float*)d_in[12];
    const int*   ei   = (const int*)d_in[13];

    char* ws = (char*)d_ws;
    // Pool layout (bytes), peak 45,713,936 (proven round 10):
    //  [0,         5,120,000)  xb   bf16 [N,128]
    //  [5.12e6,   12,800,000)  h1b  bf16 [N,192]
    //  [12.8e6,   20,480,000)  xl1b bf16 [N,192]  \ dead after gather1 ->
    //  [20.48e6,  28,160,000)  xr1b bf16 [N,192]  /  xl2 bf16 [N,384] = [12.8e6, 28.16e6)
    //  [28.16e6,  43,520,000)  xr2  bf16 [N,384]
    //  [43.52e6,  45,124,104)  CSR: cnt/fill/loc/bsum/rowoff/csrsrc
    //  [45,124,112, 45,222,416)  Wt1 bf16 [384][128]
    //  [45,222,416, 45,713,936)  Wt2 bf16 [768][320]
    bf16*  xb     = (bf16*)(ws);
    bf16*  h1b    = (bf16*)(ws + 5120000);
    bf16*  xl1b   = (bf16*)(ws + 12800000);
    bf16*  xr1b   = (bf16*)(ws + 20480000);
    bf16*  xl2    = (bf16*)(ws + 12800000);   // alias over xl1b+xr1b
    bf16*  xr2    = (bf16*)(ws + 28160000);
    int*   cnt    = (int*)(ws + 43520000);
    int*   fill   = (int*)(ws + 43600000);
    int*   loc    = (int*)(ws + 43680000);
    int*   bsum   = (int*)(ws + 43760000);
    int*   rowoff = (int*)(ws + 43764096);
    int*   csrsrc = (int*)(ws + 43844104);    // +1,280,000 -> 45,124,104
    bf16*  Wt1    = (bf16*)(ws + 45124112);
    bf16*  Wt2    = (bf16*)(ws + 45222416);

    // ---- pre-pass: casts + weight transposes ----
    k_a2x<<<(NN * IN + 255) / 256, 256, 0, stream>>>(x, xb);
    k_wt<<<(HO2 * IN + 255) / 256, 256, 0, stream>>>(Wl1, Wr1, IN, HO1, Wt1);      // 384x128
    k_wt<<<(2 * HO2 * IN2 + 255) / 256, 256, 0, stream>>>(Wl2, Wr2, IN2, HO2, Wt2); // 768x320

    // ---- CSR build (shared by both layers) ----
    hipMemsetAsync(cnt, 0, NN * sizeof(int), stream);
    k_count<<<(EE + 255) / 256, 256, 0, stream>>>(ei, cnt);
    k_scanA<<<NB_SCAN, 256, 0, stream>>>(cnt, loc, bsum);
    k_scanB<<<1, 128, 0, stream>>>(bsum);
    k_scanC<<<NB_SCAN, 256, 0, stream>>>(loc, cnt, bsum, rowoff, fill);
    k_scatter<<<(EE + 255) / 256, 256, 0, stream>>>(ei, fill, csrsrc);

    // ---- layer 1 ----
    gemm_mfma<IN><<<dim3(GRIDM, HO2 / 128), 256, 0, stream>>>(
        xb, IN, (const bf16*)nullptr, 0, Wt1, bl1, br1, HO1, xl1b, xr1b);
    gather1<<<NN / 4, 256, 0, stream>>>(rowoff, csrsrc, xl1b, xr1b, att1, bias1, h1b);

    // ---- layer 2 ----
    gemm_mfma<IN2><<<dim3(GRIDM, 2 * HO2 / 128), 256, 0, stream>>>(
        xb, IN, h1b, HO1, Wt2, bl2, br2, HO2, xl2, xr2);
    gather2<<<NN / 4, 256, 0, stream>>>(rowoff, csrsrc, xl2, xr2, att2, bias2,
                                        (float*)d_out);
}